// Round 10
// baseline (433.298 us; speedup 1.0000x reference)
//
#include <hip/hip_runtime.h>

typedef unsigned short u16;
typedef unsigned int u32;
typedef __attribute__((ext_vector_type(8))) short vbf8;   // 8 bf16 = 4 VGPR
typedef __attribute__((ext_vector_type(4))) short vs4;    // 4 bf16 = 8 B
typedef __attribute__((ext_vector_type(4))) float vf4;    // MFMA acc / float4
typedef __attribute__((ext_vector_type(2))) float vf2;    // float2

// ---------- bf16 <-> f32 (bitwise; RNE on pack) ----------
__device__ __forceinline__ float b2f(u16 u) {
  union { unsigned int i; float f; } v; v.i = ((unsigned int)u) << 16; return v.f;
}
__device__ __forceinline__ u16 f2b(float f) {
  union { float f; unsigned int i; } v; v.f = f;
  unsigned int r = v.i + 0x7fffu + ((v.i >> 16) & 1u);
  return (u16)(r >> 16);
}
__device__ __forceinline__ u16 f2h(float f) {
  union { _Float16 h; u16 s; } cv; cv.h = (_Float16)f; return cv.s;
}
__device__ __forceinline__ float h2f(u16 u) {
  union { _Float16 h; u16 s; } cv; cv.s = u; return (float)cv.h;
}
// two 8B LDS reads -> one bf16x8 fragment (8B-aligned safe)
__device__ __forceinline__ vbf8 ldpair(const u16* p) {
  vs4 lo = *(const vs4*)p;
  vs4 hi = *(const vs4*)(p + 4);
  return __builtin_shufflevector(lo, hi, 0, 1, 2, 3, 4, 5, 6, 7);
}

// ---------- tiny cross-kernel state ------
__device__ float g_state[512];
#define GS_FEATWN 0      // 256
#define GS_FEATBL 256    // 128
#define GS_W3D    384    // 32
#define GS_BLEND  416    // 4
#define GS_ACCS   420    // 2

// ---------- MFMA-fragment-ordered bf16 conv weights ----------
// conv2..4 (full-K): elem (l,j) = W[oc=nt*16+(l&15)][ic=kc*32+(l>>4)*8+j][t];
//   frag idx = (kc*9+t)*NTF + nt ; ic >= I zero-pad.
// conv1 tap-pair: k = kg*8 + tp*4 + ic; pair starts {0,3,6,2} (g0), {5,8,-,-} (g1);
//   tp=1 taps {1,4,7} (g0 only); ic>=3 or dead -> 0. WN: 2 oc-chunks x 2 groups.
__device__ __align__(16) u16 g_wfrag[90624];
#define WF_WN2 0       // 18 frags (full-K)
#define WF_BL2 9216    //  9
#define WF_WN3 13824   // 36
#define WF_WN4 32256   // 72
#define WF_BL3 69120   // 18 (I=16 zero-pad)
#define WF_BL4 78336   // 18
#define WF_WN1 87552   //  4 (2 oc-chunks x 2 groups)
#define WF_BL1 89600   //  2

// ---------- output layout (fp32 elements) ----------
#define OUT_FUSED 12582912
#define OUT_TV    13014156
#define OUT_MN    13014157
#define OUT_W3D   13014158

// ---------- prep: pack all conv weights into MFMA fragment order ----------
struct P2Args { const float* w[8]; int I[8]; int ntf[8]; int base[8]; };

__global__ __launch_bounds__(256) void kprep2(P2Args a) {
  if (blockIdx.x == 0 && threadIdx.x < 256) {
    g_state[threadIdx.x] = 0.f;
    if (threadIdx.x < 128) g_state[256 + threadIdx.x] = 0.f;
  }
  int i = blockIdx.x * 256 + threadIdx.x;   // grid 354*256 = 90624 exact
  int l = 0;
  #pragma unroll
  for (int k = 1; k < 8; k++) if (i >= a.base[k]) l = k;
  int e2 = i - a.base[l];
  int frag = e2 >> 9, e = e2 & 511;
  int ll = e >> 3, j = e & 7;
  if (l < 6) {
    int NTF = a.ntf[l];
    int kc = frag / (9 * NTF);
    int r = frag - kc * 9 * NTF;
    int t = r / NTF, nt = r - t * NTF;
    int I = a.I[l];
    int oc = nt * 16 + (ll & 15);
    int ic = kc * 32 + (ll >> 4) * 8 + j;
    g_wfrag[i] = (ic < I) ? f2b(a.w[l][(oc * I + ic) * 9 + t]) : (u16)0;
  } else {
    // conv1 tap-pair packing
    int isWN = (l == 6);
    int c2 = isWN ? (frag >> 1) : 0;
    int g = isWN ? (frag & 1) : frag;
    int idx = g * 4 + (ll >> 4);
    int tp = j >> 2, ic = j & 3;
    int tap = (tp == 0)
        ? ((idx == 0) ? 0 : (idx == 1) ? 3 : (idx == 2) ? 6 :
           (idx == 3) ? 2 : (idx == 4) ? 5 : (idx == 5) ? 8 : -1)
        : ((idx == 0) ? 1 : (idx == 1) ? 4 : (idx == 2) ? 7 : -1);
    int oc = c2 * 16 + (ll & 15);
    g_wfrag[i] = (ic < 3 && tap >= 0) ? f2b(a.w[l][oc * 27 + ic * 9 + tap]) : (u16)0;
  }
}

// ---------- merged WN+BL conv1+conv2, 512 thr, 81.6 KB LDS, 2 blk/CU ----------
// xs4 [35][35][4]; h1 32-ch NG=4 for WN (full-K conv2), first half reused by BL.
__global__ __launch_bounds__(512, 4) void k12d(
    const float* __restrict__ x,
    const float* __restrict__ wb1, const float* __restrict__ wb2,
    const float* __restrict__ bb1, const float* __restrict__ bb2,
    u16* __restrict__ h2w, u16* __restrict__ h2b)
{
  __shared__ __align__(16) u16 xs4[4908];    // 35*35*4 + 8 guard = 9,816 B
  __shared__ __align__(16) u16 h1w[35904];   // [2][33][17][32] = 71,808 B
  const int tid = threadIdx.x;
  const int lane = tid & 63, wv = tid >> 6;
  const int ocl = lane & 15;
  const int kg  = lane >> 4;
  const int oy0 = blockIdx.y * 16, ox0 = blockIdx.x * 16;
  const int hy0 = 2 * oy0 - 1, hx0 = 2 * ox0 - 1;
  const float* xb = x + (size_t)blockIdx.z * 3145728u;
  u16* h2wb = h2w + (size_t)blockIdx.z * 8388608u;
  u16* h2bb = h2b + (size_t)blockIdx.z * 4194304u;

  // ---- stage x as 4-ch NHWC bf16 ----
  for (int i = tid; i < 1225; i += 512) {
    int yy = i / 35, xx = i - yy * 35;
    int gy = hy0 - 1 + yy, gx = hx0 - 1 + xx;
    vs4 v = {0, 0, 0, 0};
    if ((unsigned)gy < 1024u && (unsigned)gx < 1024u) {
      const float* pp = xb + (gy << 10) + gx;
      v[0] = (short)f2b(pp[0]);
      v[1] = (short)f2b(pp[1048576]);
      v[2] = (short)f2b(pp[2097152]);
    }
    *(vs4*)(&xs4[(yy * 35 + xx) * 4]) = v;
  }

  // tap-pair B-frag u16 offsets (35-wide rows)
  const int to0 = (kg < 3) ? kg * 140 : 8;        // pair starts taps {0,3,6,2}
  const int to1 = (kg == 0) ? 148 : 288;          // {5,8,dead,dead}

  // WN conv1 weight frags + biases
  vbf8 waW[4];
  float bias1[2][4];
  {
    const u16* wfb = g_wfrag + WF_WN1 + lane * 8;
    #pragma unroll
    for (int q = 0; q < 4; q++) waW[q] = *(const vbf8*)(wfb + q * 512);
    #pragma unroll
    for (int j = 0; j < 4; j++) {
      bias1[0][j] = wb1[kg * 4 + j];
      bias1[1][j] = wb1[16 + kg * 4 + j];
    }
  }
  __syncthreads();

  // ---- conv1 WN: both oc-chunks, shared B-frags ----
  for (int pt = wv; pt < 69; pt += 8) {
    const int p = pt * 16 + ocl;
    const bool ok = (p < 1089);
    const int pc = ok ? p : 1088;
    const int py = pc / 33, px = pc - py * 33;
    const u16* pb = xs4 + (py * 35 + px) * 4;
    vbf8 b0 = ldpair(pb + to0);
    vbf8 b1 = ldpair(pb + to1);
    const int par = px & 1, hx = px >> 1;
    const int f = (hx >> 1) & 3;
    const int hb = ((par * 33 + py) * 17 + hx) * 32;
    #pragma unroll
    for (int c = 0; c < 2; c++) {
      vf4 acc = {0.f, 0.f, 0.f, 0.f};
      acc = __builtin_amdgcn_mfma_f32_16x16x32_bf16(waW[c * 2 + 0], b0, acc, 0, 0, 0);
      acc = __builtin_amdgcn_mfma_f32_16x16x32_bf16(waW[c * 2 + 1], b1, acc, 0, 0, 0);
      if (ok) {
        vs4 pk;
        #pragma unroll
        for (int j = 0; j < 4; j++)
          pk[j] = (short)f2b(fmaxf(acc[j] + bias1[c][j], 0.f));
        const int q = (c << 2) + kg;
        *(vs4*)(&h1w[hb + ((q >> 1) ^ f) * 8 + (q & 1) * 4]) = pk;
      }
    }
  }
  __syncthreads();

  // ---- conv2 WN: full-K (NT=2, NG=4) ----
  {
    vbf8 bw[18];
    const u16* wfb = g_wfrag + WF_WN2 + lane * 8;
    #pragma unroll
    for (int i = 0; i < 18; i++)
      bw[i] = *(const vbf8*)(wfb + i * 512);

    vf4 acc2[2][2];
    #pragma unroll
    for (int nt = 0; nt < 2; nt++) {
      float bv = wb2[nt * 16 + ocl];
      vf4 cc; cc[0] = bv; cc[1] = bv; cc[2] = bv; cc[3] = bv;
      acc2[0][nt] = cc; acc2[1][nt] = cc;
    }
    #pragma unroll
    for (int t = 0; t < 9; t++) {
      const int ty = t / 3, tx = t % 3;
      const int par = tx & 1;
      const int hx = ocl + (tx >> 1);
      const int f = (hx >> 1) & 3;
      #pragma unroll
      for (int mt = 0; mt < 2; mt++) {
        const int y = 2 * (wv * 2 + mt) + ty;
        vbf8 a = *(const vbf8*)(&h1w[((par * 33 + y) * 17 + hx) * 32 + ((kg ^ f) & 3) * 8]);
        #pragma unroll
        for (int nt = 0; nt < 2; nt++)
          acc2[mt][nt] = __builtin_amdgcn_mfma_f32_16x16x32_bf16(
              a, bw[t * 2 + nt], acc2[mt][nt], 0, 0, 0);
      }
    }
    #pragma unroll
    for (int mt = 0; mt < 2; mt++) {
      const int oy = oy0 + wv * 2 + mt;
      #pragma unroll
      for (int nt = 0; nt < 2; nt++)
        #pragma unroll
        for (int j = 0; j < 4; j++) {
          const int ox = ox0 + kg * 4 + j;
          h2wb[((size_t)(oy << 9) + ox) * 32 + nt * 16 + ocl] =
              f2b(fmaxf(acc2[mt][nt][j], 0.f));
        }
    }
  }
  __syncthreads();

  // ---- conv1 BL (writes first half of h1w as [2][33][17][16]) ----
  {
    vbf8 wa0 = *(const vbf8*)(g_wfrag + WF_BL1 + lane * 8);
    vbf8 wa1 = *(const vbf8*)(g_wfrag + WF_BL1 + 512 + lane * 8);
    float bias[4];
    #pragma unroll
    for (int j = 0; j < 4; j++) bias[j] = bb1[kg * 4 + j];
    for (int pt = wv; pt < 69; pt += 8) {
      const int p = pt * 16 + ocl;
      const bool ok = (p < 1089);
      const int pc = ok ? p : 1088;
      const int py = pc / 33, px = pc - py * 33;
      const u16* pb = xs4 + (py * 35 + px) * 4;
      vbf8 b0 = ldpair(pb + to0);
      vbf8 b1 = ldpair(pb + to1);
      vf4 acc = {0.f, 0.f, 0.f, 0.f};
      acc = __builtin_amdgcn_mfma_f32_16x16x32_bf16(wa0, b0, acc, 0, 0, 0);
      acc = __builtin_amdgcn_mfma_f32_16x16x32_bf16(wa1, b1, acc, 0, 0, 0);
      if (ok) {
        vs4 pk;
        #pragma unroll
        for (int j = 0; j < 4; j++)
          pk[j] = (short)f2b(fmaxf(acc[j] + bias[j], 0.f));
        const int par = px & 1, hx = px >> 1, f = (hx >> 2) & 1;
        *(vs4*)(&h1w[((par * 33 + py) * 17 + hx) * 16 + ((kg >> 1) ^ f) * 8 + (kg & 1) * 4]) = pk;
      }
    }
  }
  __syncthreads();

  // ---- conv2 BL (NT=1, NG=2) ----
  {
    vbf8 bw[9];
    const u16* wfb = g_wfrag + WF_BL2 + lane * 8;
    #pragma unroll
    for (int i = 0; i < 9; i++)
      bw[i] = *(const vbf8*)(wfb + i * 512);
    vf4 accB[2];
    {
      float bv = bb2[ocl];
      vf4 cc; cc[0] = bv; cc[1] = bv; cc[2] = bv; cc[3] = bv;
      accB[0] = cc; accB[1] = cc;
    }
    #pragma unroll
    for (int t = 0; t < 9; t++) {
      const int ty = t / 3, tx = t % 3;
      const int par = tx & 1;
      const int hx = ocl + (tx >> 1);
      const int f = (hx >> 2) & 1;
      #pragma unroll
      for (int mt = 0; mt < 2; mt++) {
        const int y = 2 * (wv * 2 + mt) + ty;
        const u16* ap = (kg < 2)
            ? &h1w[((par * 33 + y) * 17 + hx) * 16 + ((kg ^ f) & 1) * 8]
            : h1w;   // dead lanes: weights are zero
        vbf8 a = *(const vbf8*)ap;
        accB[mt] = __builtin_amdgcn_mfma_f32_16x16x32_bf16(a, bw[t], accB[mt], 0, 0, 0);
      }
    }
    #pragma unroll
    for (int mt = 0; mt < 2; mt++) {
      const int oy = oy0 + wv * 2 + mt;
      #pragma unroll
      for (int j = 0; j < 4; j++) {
        const int ox = ox0 + kg * 4 + j;
        h2bb[((size_t)(oy << 9) + ox) * 16 + ocl] = f2b(fmaxf(accB[mt][j], 0.f));
      }
    }
  }
}

// ---------- stride-2 conv body (conv3/conv4), NHWC in, 512 threads ----------
template<int CIN, int COUT, int NT, int NG, int KC, bool REDUCE>
__device__ __forceinline__ void k34body(
    const u16* __restrict__ in, const float* __restrict__ bia,
    int wfo, u16* __restrict__ out, int HIN, int gofs, int zb2, int og,
    u16* h1p, u16* zbuf, float* rsum)
{
  constexpr int FS = (NG == 4) ? 1 : 2;
  constexpr int NTF = COUT / 16;
  constexpr int RS = NG * 8;
  const int HO = HIN >> 1;
  const int tid = threadIdx.x;
  const int lane = tid & 63, wv = tid >> 6;
  const int oy0 = blockIdx.y * 16, ox0 = blockIdx.x * 16;
  const int iy0 = 2 * oy0 - 1, ix0 = 2 * ox0 - 1;
  const u16* inb = in + (size_t)zb2 * (size_t)HIN * HIN * CIN;

  if (tid < 8) zbuf[tid] = 0;
  if (REDUCE && tid < NT * 16) rsum[tid] = 0.f;

  const int ocl = lane & 15;
  const int kg  = lane >> 4;

  vf4 acc2[2][NT];
  #pragma unroll
  for (int nt = 0; nt < NT; nt++) {
    float bv = bia[og * NT * 16 + nt * 16 + ocl];
    #pragma unroll
    for (int mt = 0; mt < 2; mt++) {
      vf4 c; c[0] = bv; c[1] = bv; c[2] = bv; c[3] = bv;
      acc2[mt][nt] = c;
    }
  }

  vbf8 bw[9 * NT];

  for (int kc = 0; kc < KC; kc++) {
    if (kc) __syncthreads();
    for (int i = tid; i < 33 * 33 * NG; i += 512) {
      int g = i & (NG - 1);
      int pp = i / NG;
      int yy = pp / 33, xx = pp - yy * 33;
      int gy = iy0 + yy, gx = ix0 + xx;
      vbf8 v = {0, 0, 0, 0, 0, 0, 0, 0};
      if ((unsigned)gy < (unsigned)HIN && (unsigned)gx < (unsigned)HIN)
        v = *(const vbf8*)(inb + (size_t)(gy * HIN + gx) * CIN + kc * 32 + g * 8);
      const int par = xx & 1, hx = xx >> 1;
      const int f = (hx >> FS) & (NG - 1);
      *(vbf8*)(&h1p[((par * 33 + yy) * 17 + hx) * RS + (g ^ f) * 8]) = v;
    }
    {
      const u16* wfb = g_wfrag + wfo + lane * 8;
      #pragma unroll
      for (int t = 0; t < 9; t++)
        #pragma unroll
        for (int nt = 0; nt < NT; nt++)
          bw[t * NT + nt] =
              *(const vbf8*)(wfb + (size_t)((kc * 9 + t) * NTF + og * NT + nt) * 512);
    }
    __syncthreads();

    #pragma unroll
    for (int t = 0; t < 9; t++) {
      const int ty = t / 3, tx = t % 3;
      const int par = tx & 1;
      const int hx = (lane & 15) + (tx >> 1);
      const int f = (hx >> FS) & (NG - 1);
      #pragma unroll
      for (int mt = 0; mt < 2; mt++) {
        const int y = 2 * (wv * 2 + mt) + ty;
        const u16* ap;
        if constexpr (NG == 4) {
          ap = &h1p[((par * 33 + y) * 17 + hx) * RS + ((kg ^ f) & 3) * 8];
        } else {
          ap = (kg < NG) ? &h1p[((par * 33 + y) * 17 + hx) * RS + ((kg ^ f) & (NG - 1)) * 8]
                         : zbuf;
        }
        vbf8 a = *(const vbf8*)ap;
        #pragma unroll
        for (int nt = 0; nt < NT; nt++)
          acc2[mt][nt] = __builtin_amdgcn_mfma_f32_16x16x32_bf16(
              a, bw[t * NT + nt], acc2[mt][nt], 0, 0, 0);
      }
    }
  }

  if constexpr (REDUCE) {
    #pragma unroll
    for (int nt = 0; nt < NT; nt++) {
      float part = 0.f;
      #pragma unroll
      for (int mt = 0; mt < 2; mt++)
        #pragma unroll
        for (int j = 0; j < 4; j++)
          part += fmaxf(acc2[mt][nt][j], 0.f);
      atomicAdd(&rsum[nt * 16 + ocl], part);
    }
    __syncthreads();
    if (tid < NT * 16)
      atomicAdd(&g_state[gofs + zb2 * COUT + og * NT * 16 + tid],
                rsum[tid] * (1.f / 16384.f));
  } else {
    #pragma unroll
    for (int mt = 0; mt < 2; mt++) {
      const int oy = oy0 + wv * 2 + mt;
      #pragma unroll
      for (int nt = 0; nt < NT; nt++) {
        const int oc = og * NT * 16 + nt * 16 + ocl;
        #pragma unroll
        for (int j = 0; j < 4; j++) {
          const int ox = ox0 + kg * 4 + j;
          out[((size_t)zb2 * HO * HO + (size_t)(oy * HO + ox)) * COUT + oc] =
              f2b(fmaxf(acc2[mt][nt][j], 0.f));
        }
      }
    }
  }
}

// ---------- merged conv3 (WN z<zwn, BL else) ----------
__global__ __launch_bounds__(512, 2) void kc3(
    const u16* __restrict__ inW, const float* __restrict__ bW, u16* __restrict__ outW,
    const u16* __restrict__ inB, const float* __restrict__ bB, u16* __restrict__ outB,
    int zwn)
{
  __shared__ __align__(16) u16 h1sh[35904];
  __shared__ __align__(16) u16 zbuf[8];
  __shared__ float rsum[32];
  const int z = blockIdx.z;
  if (z < zwn)
    k34body<32, 64, 2, 4, 1, false>(inW, bW, WF_WN3, outW, 512, 0, z >> 1, z & 1,
                                    h1sh, zbuf, rsum);
  else
    k34body<16, 32, 2, 2, 1, false>(inB, bB, WF_BL3, outB, 512, 0, z - zwn, 0,
                                    h1sh, zbuf, rsum);
}

// ---------- merged conv4 (WN z<zwn, BL else), fused mean-reduce ----------
__global__ __launch_bounds__(512, 2) void kc4(
    const u16* __restrict__ inW, const float* __restrict__ bW, int gofsW,
    const u16* __restrict__ inB, const float* __restrict__ bB, int gofsB,
    int zwn)
{
  __shared__ __align__(16) u16 h1sh[35904];
  __shared__ __align__(16) u16 zbuf[8];
  __shared__ float rsum[32];
  const int z = blockIdx.z;
  if (z < zwn)
    k34body<64, 64, 2, 4, 2, true>(inW, bW, WF_WN4, nullptr, 256, gofsW, z >> 1, z & 1,
                                   h1sh, zbuf, rsum);
  else
    k34body<32, 32, 2, 4, 1, true>(inB, bB, WF_BL4, nullptr, 256, gofsB, z - zwn, 0,
                                   h1sh, zbuf, rsum);
}

// ---------- FC heads (merged) ----------
template<int CF, int NOUT, bool SIG>
__device__ __forceinline__ void khead_body(
    const float* __restrict__ fw1, const float* __restrict__ fb1,
    const float* __restrict__ fw2, const float* __restrict__ fb2,
    int feato, int outo, float* out_f, float* fc1)
{
  const int tid = threadIdx.x;
  if (tid < 4 * CF) {
    int b = tid / CF, o = tid - b * CF;
    float s = fb1[o];
    for (int i = 0; i < CF; i++)
      s = fmaf(g_state[feato + b * CF + i], fw1[o * CF + i], s);
    fc1[tid] = fmaxf(s, 0.f);
  }
  __syncthreads();
  if (tid < 4 * NOUT) {
    int b = tid / NOUT, n = tid - b * NOUT;
    float s = fb2[n];
    for (int i = 0; i < CF; i++)
      s = fmaf(fc1[b * CF + i], fw2[n * CF + i], s);
    if (SIG) s = 1.f / (1.f + expf(-s));
    g_state[outo + b * NOUT + n] = s;
    if (out_f) out_f[b * NOUT + n] = s;
  }
}

__global__ __launch_bounds__(256) void kheads(
    const float* __restrict__ wfw1, const float* __restrict__ wfb1,
    const float* __restrict__ wfw2, const float* __restrict__ wfb2,
    const float* __restrict__ bfw1, const float* __restrict__ bfb1,
    const float* __restrict__ bfw2, const float* __restrict__ bfb2,
    float* out_w3d)
{
  __shared__ float fc1[256];
  if (blockIdx.x == 0)
    khead_body<64, 8, false>(wfw1, wfb1, wfw2, wfb2, GS_FEATWN, GS_W3D, out_w3d, fc1);
  else
    khead_body<32, 1, true>(bfw1, bfb1, bfw2, bfb2, GS_FEATBL, GS_BLEND, nullptr, fc1);
}

// ---------- fused LUT = clip(w3d @ luts + identity, 0,1); also fp16 AoS copy ----------
__global__ __launch_bounds__(256) void kfuse(
    const float* __restrict__ luts, float* __restrict__ outF,
    u16* __restrict__ Fa)
{
  if (blockIdx.x == 0 && threadIdx.x == 0) {
    g_state[GS_ACCS] = 0.f; g_state[GS_ACCS + 1] = 0.f;
  }
  int idx = blockIdx.x * 256 + threadIdx.x;
  if (idx >= 431244) return;
  int n = idx / 107811, m = idx - n * 107811;
  int c = m / 35937, q = m - c * 35937;
  int bq = q / 1089, r2 = q - bq * 1089;
  int gq = r2 / 33, rq = r2 - gq * 33;
  int id = (c == 0) ? rq : (c == 1) ? gq : bq;
  float s = (float)id * (1.f / 32.f);
  #pragma unroll
  for (int k = 0; k < 8; k++)
    s = fmaf(g_state[GS_W3D + n * 8 + k], luts[k * 107811 + m], s);
  s = fminf(fmaxf(s, 0.f), 1.f);
  outF[idx] = s;
  if (Fa) Fa[(n * 35937 + q) * 4 + c] = f2h(s);
}

// ---------- TV + monotonicity reductions over fused ----------
__global__ __launch_bounds__(256) void ktv(const float* __restrict__ f) {
  const int Nr = 418176;
  float tv = 0.f, mn = 0.f;
  for (int e = blockIdx.x * 256 + threadIdx.x; e < 3 * Nr; e += gridDim.x * 256) {
    int dir = e / Nr, j = e - dir * Nr;
    int i, stride; float w;
    if (dir == 0) {
      int r = j & 31; int t = j >> 5;
      int g = t % 33; t /= 33;
      i = t * 1089 + g * 33 + r; stride = 1;
      w = (r == 0 || r == 31) ? 2.f : 1.f;
    } else if (dir == 1) {
      int r = j % 33; int t = j / 33; int g = t & 31; t >>= 5;
      i = t * 1089 + g * 33 + r; stride = 33;
      w = (g == 0 || g == 31) ? 2.f : 1.f;
    } else {
      int r = j % 33; int t = j / 33; int g = t % 33; t /= 33;
      int bb = t & 31; t >>= 5;
      i = (t * 33 + bb) * 1089 + g * 33 + r; stride = 1089;
      w = (bb == 0 || bb == 31) ? 2.f : 1.f;
    }
    float d = f[i] - f[i + stride];
    tv = fmaf(d * d, w, tv);
    mn += fmaxf(d, 0.f);
  }
  __shared__ float r1[256], r2[256];
  r1[threadIdx.x] = tv; r2[threadIdx.x] = mn; __syncthreads();
  for (int st = 128; st > 0; st >>= 1) {
    if (threadIdx.x < st) { r1[threadIdx.x] += r1[threadIdx.x + st];
                            r2[threadIdx.x] += r2[threadIdx.x + st]; }
    __syncthreads();
  }
  if (threadIdx.x == 0) {
    atomicAdd(&g_state[GS_ACCS], r1[0]);
    atomicAdd(&g_state[GS_ACCS + 1], r2[0]);
  }
}

// ---------- trilinear apply, 2x2 px/thread on 32x32 tiles, fp16 AoS LUT ----------
// Wave footprint = 32x8 pixel patch -> lanes' LUT gathers share cache lines.
__global__ __launch_bounds__(256) void kapply4(
    const float* __restrict__ x, const u16* __restrict__ Fa,
    float* __restrict__ out)
{
  if (blockIdx.x == 0 && blockIdx.y == 0 && blockIdx.z == 0 && threadIdx.x == 0) {
    out[OUT_TV] = g_state[GS_ACCS] * (1.f / 418176.f);
    out[OUT_MN] = g_state[GS_ACCS + 1] * (1.f / 418176.f);
  }
  const int b = blockIdx.z;
  const int tx = threadIdx.x & 15, ty = threadIdx.x >> 4;
  const int px0 = blockIdx.x * 32 + tx * 2;
  const int py0 = blockIdx.y * 32 + ty * 2;
  const float a = g_state[GS_BLEND + b];
  const u32* Fu = (const u32*)Fa;
  const size_t xb0 = (size_t)b * 3145728u;

  vf2 xr[2], xg[2], xbl[2];
  #pragma unroll
  for (int r = 0; r < 2; r++) {
    size_t base = xb0 + (size_t)((py0 + r) << 10) + px0;
    xr[r]  = *(const vf2*)(x + base);
    xg[r]  = *(const vf2*)(x + base + 1048576);
    xbl[r] = *(const vf2*)(x + base + 2097152);
  }

  int cb4[4];
  float fr4[4], fg4[4], fb4[4], xv4[4][3];
  #pragma unroll
  for (int r = 0; r < 2; r++)
    #pragma unroll
    for (int cq = 0; cq < 2; cq++) {
      const int i = r * 2 + cq;
      float vr = xr[r][cq], vg = xg[r][cq], vb = xbl[r][cq];
      xv4[i][0] = vr; xv4[i][1] = vg; xv4[i][2] = vb;
      float sr = fminf(fmaxf(vr, 0.f), 1.f) * 32.f;
      float sg = fminf(fmaxf(vg, 0.f), 1.f) * 32.f;
      float sb = fminf(fmaxf(vb, 0.f), 1.f) * 32.f;
      int ir = min((int)sr, 31), ig = min((int)sg, 31), ib = min((int)sb, 31);
      fr4[i] = sr - ir; fg4[i] = sg - ig; fb4[i] = sb - ib;
      cb4[i] = b * 35937 + ib * 1089 + ig * 33 + ir;
    }

  // 16 independent dwordx4 gathers (4 corner-pairs x 4 pixels)
  u32 q[4][4][4];
  const int off[4] = {0, 33, 1089, 1122};
  #pragma unroll
  for (int i = 0; i < 4; i++)
    #pragma unroll
    for (int pr = 0; pr < 4; pr++) {
      const u32* c0 = Fu + (size_t)(cb4[i] + off[pr]) * 2;
      q[i][pr][0] = c0[0]; q[i][pr][1] = c0[1];
      q[i][pr][2] = c0[2]; q[i][pr][3] = c0[3];
    }

  vf2 o0[2], o1[2], o2[2];
  #pragma unroll
  for (int r = 0; r < 2; r++)
    #pragma unroll
    for (int cq = 0; cq < 2; cq++) {
      const int i = r * 2 + cq;
      const float fr = fr4[i], fg = fg4[i], fb = fb4[i];
      #pragma unroll
      for (int c = 0; c < 3; c++) {
        const int k = c >> 1, sh = (c & 1) * 16;
        float v000 = h2f((u16)(q[i][0][k]     >> sh));
        float v001 = h2f((u16)(q[i][0][2 + k] >> sh));
        float v010 = h2f((u16)(q[i][1][k]     >> sh));
        float v011 = h2f((u16)(q[i][1][2 + k] >> sh));
        float v100 = h2f((u16)(q[i][2][k]     >> sh));
        float v101 = h2f((u16)(q[i][2][2 + k] >> sh));
        float v110 = h2f((u16)(q[i][3][k]     >> sh));
        float v111 = h2f((u16)(q[i][3][2 + k] >> sh));
        float c00 = v000 + fr * (v001 - v000);
        float c01 = v010 + fr * (v011 - v010);
        float c10 = v100 + fr * (v101 - v100);
        float c11 = v110 + fr * (v111 - v110);
        float c0 = c00 + fg * (c01 - c00);
        float c1 = c10 + fg * (c11 - c10);
        float v  = c0 + fb * (c1 - c0);
        float o = fminf(fmaxf((1.f - a) * xv4[i][c] + a * v, 0.f), 1.f);
        if (c == 0) o0[r][cq] = o; else if (c == 1) o1[r][cq] = o; else o2[r][cq] = o;
      }
    }
  #pragma unroll
  for (int r = 0; r < 2; r++) {
    size_t base = (size_t)((py0 + r) << 10) + px0;
    *(vf2*)(out + (size_t)(b * 3 + 0) * 1048576u + base) = o0[r];
    *(vf2*)(out + (size_t)(b * 3 + 1) * 1048576u + base) = o1[r];
    *(vf2*)(out + (size_t)(b * 3 + 2) * 1048576u + base) = o2[r];
  }
}

// ---------- trilinear apply, fallback 1 px/thread, fp32 SoA ----------
__global__ __launch_bounds__(256) void kapply1(
    const float* __restrict__ x, const float* __restrict__ F,
    float* __restrict__ out)
{
  int p = blockIdx.x * 256 + threadIdx.x;
  if (p == 0) {
    out[OUT_TV] = g_state[GS_ACCS] * (1.f / 418176.f);
    out[OUT_MN] = g_state[GS_ACCS + 1] * (1.f / 418176.f);
  }
  int b = p >> 20, yx = p & 1048575;
  size_t base = (size_t)b * 3145728u + yx;
  float xr = x[base];
  float xg = x[base + 1048576];
  float xb = x[base + 2097152];
  float a = g_state[GS_BLEND + b];
  float sr = fminf(fmaxf(xr, 0.f), 1.f) * 32.f;
  float sg = fminf(fmaxf(xg, 0.f), 1.f) * 32.f;
  float sb = fminf(fmaxf(xb, 0.f), 1.f) * 32.f;
  int ir = min((int)sr, 31), ig = min((int)sg, 31), ib = min((int)sb, 31);
  float fr = sr - ir, fg = sg - ig, fb = sb - ib;
  const float* Fb = F + (size_t)b * 107811u + ib * 1089 + ig * 33 + ir;
  #pragma unroll
  for (int c = 0; c < 3; c++) {
    const float* Fc = Fb + c * 35937;
    float v000 = Fc[0],    v001 = Fc[1];
    float v010 = Fc[33],   v011 = Fc[34];
    float v100 = Fc[1089], v101 = Fc[1090];
    float v110 = Fc[1122], v111 = Fc[1123];
    float c00 = v000 + fr * (v001 - v000);
    float c01 = v010 + fr * (v011 - v010);
    float c10 = v100 + fr * (v101 - v100);
    float c11 = v110 + fr * (v111 - v110);
    float c0 = c00 + fg * (c01 - c00);
    float c1 = c10 + fg * (c11 - c10);
    float v  = c0 + fb * (c1 - c0);
    float xv = (c == 0) ? xr : (c == 1) ? xg : xb;
    float o = fminf(fmaxf((1.f - a) * xv + a * v, 0.f), 1.f);
    out[(size_t)(b * 3 + c) * 1048576u + yx] = o;
  }
}

extern "C" void kernel_launch(void* const* d_in, const int* in_sizes, int n_in,
                              void* d_out, int out_size, void* d_ws, size_t ws_size,
                              hipStream_t stream)
{
  (void)in_sizes; (void)n_in; (void)out_size;
  const float* x    = (const float*)d_in[0];
  const float* luts = (const float*)d_in[1];
  const float* wn_b1 = (const float*)d_in[3];
  const float* wn_b2 = (const float*)d_in[5];
  const float* wn_b3 = (const float*)d_in[7];
  const float* wn_b4 = (const float*)d_in[9];
  const float* wn_fw1 = (const float*)d_in[10], *wn_fb1 = (const float*)d_in[11];
  const float* wn_fw2 = (const float*)d_in[12], *wn_fb2 = (const float*)d_in[13];
  const float* bl_b1 = (const float*)d_in[15];
  const float* bl_b2 = (const float*)d_in[17];
  const float* bl_b3 = (const float*)d_in[19];
  const float* bl_b4 = (const float*)d_in[21];
  const float* bl_fw1 = (const float*)d_in[22], *bl_fb1 = (const float*)d_in[23];
  const float* bl_fw2 = (const float*)d_in[24], *bl_fb2 = (const float*)d_in[25];
  float* out = (float*)d_out;
  const bool hasWs = (ws_size >= 50331648u);

  P2Args p2;
  const float* wsrc[8] = {(const float*)d_in[4],  (const float*)d_in[16],
                          (const float*)d_in[6],  (const float*)d_in[8],
                          (const float*)d_in[18], (const float*)d_in[20],
                          (const float*)d_in[2],  (const float*)d_in[14]};
  const int pI[8]   = {32, 16, 32, 64, 16, 32, 3, 3};
  const int pNTF[8] = {2, 1, 4, 4, 2, 2, 2, 1};
  const int pB[8]   = {WF_WN2, WF_BL2, WF_WN3, WF_WN4, WF_BL3, WF_BL4,
                       WF_WN1, WF_BL1};
  for (int l = 0; l < 8; l++) { p2.w[l] = wsrc[l]; p2.I[l] = pI[l];
                                p2.ntf[l] = pNTF[l]; p2.base[l] = pB[l]; }
  kprep2<<<dim3(354), 256, 0, stream>>>(p2);

  if (hasWs) {
    u16* scrA = (u16*)d_ws;                    // WN h2, 2 batches (33.6 MB)
    u16* scrB = (u16*)d_ws + 16777216;         // WN conv3 out (16.8 MB)
    u16* blh2 = (u16*)out;                     // BL h2, 2 batches (16.8 MB)
    u16* blc3 = (u16*)out + 8388608;           // BL conv3 out (8.4 MB)
    u16* Fa   = (u16*)d_ws;                    // fp16 AoS LUT (post-conv)

    for (int b0 = 0; b0 < 4; b0 += 2) {
      const float* xb = x + (size_t)b0 * 3145728u;
      k12d<<<dim3(32,32,2), 512, 0, stream>>>(xb, wn_b1, wn_b2, bl_b1, bl_b2,
                                              scrA, blh2);
      kc3<<<dim3(16,16,6), 512, 0, stream>>>(scrA, wn_b3, scrB,
                                             blh2, bl_b3, blc3, 4);
      kc4<<<dim3(8,8,6),   512, 0, stream>>>(scrB, wn_b4, GS_FEATWN + b0 * 64,
                                             blc3, bl_b4, GS_FEATBL + b0 * 32, 4);
    }
    kheads<<<2, 256, 0, stream>>>(wn_fw1, wn_fb1, wn_fw2, wn_fb2,
                                  bl_fw1, bl_fb1, bl_fw2, bl_fb2, out + OUT_W3D);

    kfuse<<<1685, 256, 0, stream>>>(luts, out + OUT_FUSED, Fa);
    ktv<<<512, 256, 0, stream>>>(out + OUT_FUSED);
    kapply4<<<dim3(32,32,4), 256, 0, stream>>>(x, Fa, out);
  } else {
    // 1-batch passes; all scratch inside d_out (37.7 MB < OUT_FUSED @ 50.3 MB)
    u16* h2wF  = (u16*)out;                 // 16.8 MB
    u16* h2bF  = (u16*)out + 8388608;       //  8.4 MB
    u16* wnc3F = (u16*)out + 12582912;      //  8.4 MB
    u16* blc3F = (u16*)out + 16777216;      //  4.2 MB

    for (int b = 0; b < 4; b++) {
      const float* xb = x + (size_t)b * 3145728u;
      k12d<<<dim3(32,32,1), 512, 0, stream>>>(xb, wn_b1, wn_b2, bl_b1, bl_b2,
                                              h2wF, h2bF);
      kc3<<<dim3(16,16,3), 512, 0, stream>>>(h2wF, wn_b3, wnc3F,
                                             h2bF, bl_b3, blc3F, 2);
      kc4<<<dim3(8,8,3),   512, 0, stream>>>(wnc3F, wn_b4, GS_FEATWN + b * 64,
                                             blc3F, bl_b4, GS_FEATBL + b * 32, 2);
    }
    kheads<<<2, 256, 0, stream>>>(wn_fw1, wn_fb1, wn_fw2, wn_fb2,
                                  bl_fw1, bl_fb1, bl_fw2, bl_fb2, out + OUT_W3D);

    kfuse<<<1685, 256, 0, stream>>>(luts, out + OUT_FUSED, nullptr);
    ktv<<<512, 256, 0, stream>>>(out + OUT_FUSED);
    kapply1<<<16384, 256, 0, stream>>>(x, out + OUT_FUSED, out);
  }
}

// Round 11
// 418.978 us; speedup vs baseline: 1.0342x; 1.0342x over previous
//
#include <hip/hip_runtime.h>

typedef unsigned short u16;
typedef unsigned int u32;
typedef __attribute__((ext_vector_type(8))) short vbf8;   // 8 bf16 = 4 VGPR
typedef __attribute__((ext_vector_type(4))) short vs4;    // 4 bf16 = 8 B
typedef __attribute__((ext_vector_type(4))) float vf4;    // MFMA acc / float4
typedef __attribute__((ext_vector_type(2))) float vf2;    // float2

// ---------- bf16 <-> f32 (bitwise; RNE on pack) ----------
__device__ __forceinline__ float b2f(u16 u) {
  union { unsigned int i; float f; } v; v.i = ((unsigned int)u) << 16; return v.f;
}
__device__ __forceinline__ u16 f2b(float f) {
  union { float f; unsigned int i; } v; v.f = f;
  unsigned int r = v.i + 0x7fffu + ((v.i >> 16) & 1u);
  return (u16)(r >> 16);
}
__device__ __forceinline__ u16 f2h(float f) {
  union { _Float16 h; u16 s; } cv; cv.h = (_Float16)f; return cv.s;
}
__device__ __forceinline__ float h2f(u16 u) {
  union { _Float16 h; u16 s; } cv; cv.s = u; return (float)cv.h;
}
// two 8B LDS reads -> one bf16x8 fragment (8B-aligned safe)
__device__ __forceinline__ vbf8 ldpair(const u16* p) {
  vs4 lo = *(const vs4*)p;
  vs4 hi = *(const vs4*)(p + 4);
  return __builtin_shufflevector(lo, hi, 0, 1, 2, 3, 4, 5, 6, 7);
}

// ---------- tiny cross-kernel state ------
__device__ float g_state[512];
#define GS_FEATWN 0      // 256
#define GS_FEATBL 256    // 128
#define GS_W3D    384    // 32
#define GS_BLEND  416    // 4
#define GS_ACCS   420    // 2

// ---------- MFMA-fragment-ordered bf16 conv weights ----------
// conv2..4 (full-K): elem (l,j) = W[oc=nt*16+(l&15)][ic=kc*32+(l>>4)*8+j][t];
//   frag idx = (kc*9+t)*NTF + nt ; ic >= I zero-pad.
// conv1 tap-pair: k = kg*8 + tp*4 + ic; pair starts {0,3,6,2} (g0), {5,8,-,-} (g1);
//   tp=1 taps {1,4,7} (g0 only); ic>=3 or dead -> 0. WN: 2 oc-chunks x 2 groups.
__device__ __align__(16) u16 g_wfrag[90624];
#define WF_WN2 0       // 18 frags (full-K)
#define WF_BL2 9216    //  9
#define WF_WN3 13824   // 36
#define WF_WN4 32256   // 72
#define WF_BL3 69120   // 18 (I=16 zero-pad)
#define WF_BL4 78336   // 18
#define WF_WN1 87552   //  4 (2 oc-chunks x 2 groups)
#define WF_BL1 89600   //  2

// ---------- output layout (fp32 elements) ----------
#define OUT_FUSED 12582912
#define OUT_TV    13014156
#define OUT_MN    13014157
#define OUT_W3D   13014158

// ---------- prep: pack all conv weights into MFMA fragment order ----------
struct P2Args { const float* w[8]; int I[8]; int ntf[8]; int base[8]; };

__global__ __launch_bounds__(256) void kprep2(P2Args a) {
  if (blockIdx.x == 0 && threadIdx.x < 256) {
    g_state[threadIdx.x] = 0.f;
    if (threadIdx.x < 128) g_state[256 + threadIdx.x] = 0.f;
  }
  int i = blockIdx.x * 256 + threadIdx.x;   // grid 354*256 = 90624 exact
  int l = 0;
  #pragma unroll
  for (int k = 1; k < 8; k++) if (i >= a.base[k]) l = k;
  int e2 = i - a.base[l];
  int frag = e2 >> 9, e = e2 & 511;
  int ll = e >> 3, j = e & 7;
  if (l < 6) {
    int NTF = a.ntf[l];
    int kc = frag / (9 * NTF);
    int r = frag - kc * 9 * NTF;
    int t = r / NTF, nt = r - t * NTF;
    int I = a.I[l];
    int oc = nt * 16 + (ll & 15);
    int ic = kc * 32 + (ll >> 4) * 8 + j;
    g_wfrag[i] = (ic < I) ? f2b(a.w[l][(oc * I + ic) * 9 + t]) : (u16)0;
  } else {
    // conv1 tap-pair packing
    int isWN = (l == 6);
    int c2 = isWN ? (frag >> 1) : 0;
    int g = isWN ? (frag & 1) : frag;
    int idx = g * 4 + (ll >> 4);
    int tp = j >> 2, ic = j & 3;
    int tap = (tp == 0)
        ? ((idx == 0) ? 0 : (idx == 1) ? 3 : (idx == 2) ? 6 :
           (idx == 3) ? 2 : (idx == 4) ? 5 : (idx == 5) ? 8 : -1)
        : ((idx == 0) ? 1 : (idx == 1) ? 4 : (idx == 2) ? 7 : -1);
    int oc = c2 * 16 + (ll & 15);
    g_wfrag[i] = (ic < 3 && tap >= 0) ? f2b(a.w[l][oc * 27 + ic * 9 + tap]) : (u16)0;
  }
}

// ---------- merged WN+BL conv1+conv2, 512 thr, 81.6 KB LDS, 2 blk/CU ----------
// xs4 [35][35][4]; h1 32-ch NG=4 for WN (full-K conv2), first half reused by BL.
__global__ __launch_bounds__(512, 4) void k12d(
    const float* __restrict__ x,
    const float* __restrict__ wb1, const float* __restrict__ wb2,
    const float* __restrict__ bb1, const float* __restrict__ bb2,
    u16* __restrict__ h2w, u16* __restrict__ h2b)
{
  __shared__ __align__(16) u16 xs4[4908];    // 35*35*4 + 8 guard = 9,816 B
  __shared__ __align__(16) u16 h1w[35904];   // [2][33][17][32] = 71,808 B
  const int tid = threadIdx.x;
  const int lane = tid & 63, wv = tid >> 6;
  const int ocl = lane & 15;
  const int kg  = lane >> 4;
  const int oy0 = blockIdx.y * 16, ox0 = blockIdx.x * 16;
  const int hy0 = 2 * oy0 - 1, hx0 = 2 * ox0 - 1;
  const float* xb = x + (size_t)blockIdx.z * 3145728u;
  u16* h2wb = h2w + (size_t)blockIdx.z * 8388608u;
  u16* h2bb = h2b + (size_t)blockIdx.z * 4194304u;

  // ---- stage x as 4-ch NHWC bf16 ----
  for (int i = tid; i < 1225; i += 512) {
    int yy = i / 35, xx = i - yy * 35;
    int gy = hy0 - 1 + yy, gx = hx0 - 1 + xx;
    vs4 v = {0, 0, 0, 0};
    if ((unsigned)gy < 1024u && (unsigned)gx < 1024u) {
      const float* pp = xb + (gy << 10) + gx;
      v[0] = (short)f2b(pp[0]);
      v[1] = (short)f2b(pp[1048576]);
      v[2] = (short)f2b(pp[2097152]);
    }
    *(vs4*)(&xs4[(yy * 35 + xx) * 4]) = v;
  }

  // tap-pair B-frag u16 offsets (35-wide rows)
  const int to0 = (kg < 3) ? kg * 140 : 8;        // pair starts taps {0,3,6,2}
  const int to1 = (kg == 0) ? 148 : 288;          // {5,8,dead,dead}

  // WN conv1 weight frags + biases
  vbf8 waW[4];
  float bias1[2][4];
  {
    const u16* wfb = g_wfrag + WF_WN1 + lane * 8;
    #pragma unroll
    for (int q = 0; q < 4; q++) waW[q] = *(const vbf8*)(wfb + q * 512);
    #pragma unroll
    for (int j = 0; j < 4; j++) {
      bias1[0][j] = wb1[kg * 4 + j];
      bias1[1][j] = wb1[16 + kg * 4 + j];
    }
  }
  __syncthreads();

  // ---- conv1 WN: both oc-chunks, shared B-frags ----
  for (int pt = wv; pt < 69; pt += 8) {
    const int p = pt * 16 + ocl;
    const bool ok = (p < 1089);
    const int pc = ok ? p : 1088;
    const int py = pc / 33, px = pc - py * 33;
    const u16* pb = xs4 + (py * 35 + px) * 4;
    vbf8 b0 = ldpair(pb + to0);
    vbf8 b1 = ldpair(pb + to1);
    const int par = px & 1, hx = px >> 1;
    const int f = (hx >> 1) & 3;
    const int hb = ((par * 33 + py) * 17 + hx) * 32;
    #pragma unroll
    for (int c = 0; c < 2; c++) {
      vf4 acc = {0.f, 0.f, 0.f, 0.f};
      acc = __builtin_amdgcn_mfma_f32_16x16x32_bf16(waW[c * 2 + 0], b0, acc, 0, 0, 0);
      acc = __builtin_amdgcn_mfma_f32_16x16x32_bf16(waW[c * 2 + 1], b1, acc, 0, 0, 0);
      if (ok) {
        vs4 pk;
        #pragma unroll
        for (int j = 0; j < 4; j++)
          pk[j] = (short)f2b(fmaxf(acc[j] + bias1[c][j], 0.f));
        const int q = (c << 2) + kg;
        *(vs4*)(&h1w[hb + ((q >> 1) ^ f) * 8 + (q & 1) * 4]) = pk;
      }
    }
  }
  __syncthreads();

  // ---- conv2 WN: full-K (NT=2, NG=4) ----
  {
    vbf8 bw[18];
    const u16* wfb = g_wfrag + WF_WN2 + lane * 8;
    #pragma unroll
    for (int i = 0; i < 18; i++)
      bw[i] = *(const vbf8*)(wfb + i * 512);

    vf4 acc2[2][2];
    #pragma unroll
    for (int nt = 0; nt < 2; nt++) {
      float bv = wb2[nt * 16 + ocl];
      vf4 cc; cc[0] = bv; cc[1] = bv; cc[2] = bv; cc[3] = bv;
      acc2[0][nt] = cc; acc2[1][nt] = cc;
    }
    #pragma unroll
    for (int t = 0; t < 9; t++) {
      const int ty = t / 3, tx = t % 3;
      const int par = tx & 1;
      const int hx = ocl + (tx >> 1);
      const int f = (hx >> 1) & 3;
      #pragma unroll
      for (int mt = 0; mt < 2; mt++) {
        const int y = 2 * (wv * 2 + mt) + ty;
        vbf8 a = *(const vbf8*)(&h1w[((par * 33 + y) * 17 + hx) * 32 + ((kg ^ f) & 3) * 8]);
        #pragma unroll
        for (int nt = 0; nt < 2; nt++)
          acc2[mt][nt] = __builtin_amdgcn_mfma_f32_16x16x32_bf16(
              a, bw[t * 2 + nt], acc2[mt][nt], 0, 0, 0);
      }
    }
    #pragma unroll
    for (int mt = 0; mt < 2; mt++) {
      const int oy = oy0 + wv * 2 + mt;
      #pragma unroll
      for (int nt = 0; nt < 2; nt++)
        #pragma unroll
        for (int j = 0; j < 4; j++) {
          const int ox = ox0 + kg * 4 + j;
          h2wb[((size_t)(oy << 9) + ox) * 32 + nt * 16 + ocl] =
              f2b(fmaxf(acc2[mt][nt][j], 0.f));
        }
    }
  }
  __syncthreads();

  // ---- conv1 BL (writes first half of h1w as [2][33][17][16]) ----
  {
    vbf8 wa0 = *(const vbf8*)(g_wfrag + WF_BL1 + lane * 8);
    vbf8 wa1 = *(const vbf8*)(g_wfrag + WF_BL1 + 512 + lane * 8);
    float bias[4];
    #pragma unroll
    for (int j = 0; j < 4; j++) bias[j] = bb1[kg * 4 + j];
    for (int pt = wv; pt < 69; pt += 8) {
      const int p = pt * 16 + ocl;
      const bool ok = (p < 1089);
      const int pc = ok ? p : 1088;
      const int py = pc / 33, px = pc - py * 33;
      const u16* pb = xs4 + (py * 35 + px) * 4;
      vbf8 b0 = ldpair(pb + to0);
      vbf8 b1 = ldpair(pb + to1);
      vf4 acc = {0.f, 0.f, 0.f, 0.f};
      acc = __builtin_amdgcn_mfma_f32_16x16x32_bf16(wa0, b0, acc, 0, 0, 0);
      acc = __builtin_amdgcn_mfma_f32_16x16x32_bf16(wa1, b1, acc, 0, 0, 0);
      if (ok) {
        vs4 pk;
        #pragma unroll
        for (int j = 0; j < 4; j++)
          pk[j] = (short)f2b(fmaxf(acc[j] + bias[j], 0.f));
        const int par = px & 1, hx = px >> 1, f = (hx >> 2) & 1;
        *(vs4*)(&h1w[((par * 33 + py) * 17 + hx) * 16 + ((kg >> 1) ^ f) * 8 + (kg & 1) * 4]) = pk;
      }
    }
  }
  __syncthreads();

  // ---- conv2 BL (NT=1, NG=2) ----
  {
    vbf8 bw[9];
    const u16* wfb = g_wfrag + WF_BL2 + lane * 8;
    #pragma unroll
    for (int i = 0; i < 9; i++)
      bw[i] = *(const vbf8*)(wfb + i * 512);
    vf4 accB[2];
    {
      float bv = bb2[ocl];
      vf4 cc; cc[0] = bv; cc[1] = bv; cc[2] = bv; cc[3] = bv;
      accB[0] = cc; accB[1] = cc;
    }
    #pragma unroll
    for (int t = 0; t < 9; t++) {
      const int ty = t / 3, tx = t % 3;
      const int par = tx & 1;
      const int hx = ocl + (tx >> 1);
      const int f = (hx >> 2) & 1;
      #pragma unroll
      for (int mt = 0; mt < 2; mt++) {
        const int y = 2 * (wv * 2 + mt) + ty;
        const u16* ap = (kg < 2)
            ? &h1w[((par * 33 + y) * 17 + hx) * 16 + ((kg ^ f) & 1) * 8]
            : h1w;   // dead lanes: weights are zero
        vbf8 a = *(const vbf8*)ap;
        accB[mt] = __builtin_amdgcn_mfma_f32_16x16x32_bf16(a, bw[t], accB[mt], 0, 0, 0);
      }
    }
    #pragma unroll
    for (int mt = 0; mt < 2; mt++) {
      const int oy = oy0 + wv * 2 + mt;
      #pragma unroll
      for (int j = 0; j < 4; j++) {
        const int ox = ox0 + kg * 4 + j;
        h2bb[((size_t)(oy << 9) + ox) * 16 + ocl] = f2b(fmaxf(accB[mt][j], 0.f));
      }
    }
  }
}

// ---------- stride-2 conv body (conv3/conv4), NHWC in, 512 threads ----------
template<int CIN, int COUT, int NT, int NG, int KC, bool REDUCE>
__device__ __forceinline__ void k34body(
    const u16* __restrict__ in, const float* __restrict__ bia,
    int wfo, u16* __restrict__ out, int HIN, int gofs, int zb2, int og,
    u16* h1p, u16* zbuf, float* rsum)
{
  constexpr int FS = (NG == 4) ? 1 : 2;
  constexpr int NTF = COUT / 16;
  constexpr int RS = NG * 8;
  const int HO = HIN >> 1;
  const int tid = threadIdx.x;
  const int lane = tid & 63, wv = tid >> 6;
  const int oy0 = blockIdx.y * 16, ox0 = blockIdx.x * 16;
  const int iy0 = 2 * oy0 - 1, ix0 = 2 * ox0 - 1;
  const u16* inb = in + (size_t)zb2 * (size_t)HIN * HIN * CIN;

  if (tid < 8) zbuf[tid] = 0;
  if (REDUCE && tid < NT * 16) rsum[tid] = 0.f;

  const int ocl = lane & 15;
  const int kg  = lane >> 4;

  vf4 acc2[2][NT];
  #pragma unroll
  for (int nt = 0; nt < NT; nt++) {
    float bv = bia[og * NT * 16 + nt * 16 + ocl];
    #pragma unroll
    for (int mt = 0; mt < 2; mt++) {
      vf4 c; c[0] = bv; c[1] = bv; c[2] = bv; c[3] = bv;
      acc2[mt][nt] = c;
    }
  }

  vbf8 bw[9 * NT];

  for (int kc = 0; kc < KC; kc++) {
    if (kc) __syncthreads();
    for (int i = tid; i < 33 * 33 * NG; i += 512) {
      int g = i & (NG - 1);
      int pp = i / NG;
      int yy = pp / 33, xx = pp - yy * 33;
      int gy = iy0 + yy, gx = ix0 + xx;
      vbf8 v = {0, 0, 0, 0, 0, 0, 0, 0};
      if ((unsigned)gy < (unsigned)HIN && (unsigned)gx < (unsigned)HIN)
        v = *(const vbf8*)(inb + (size_t)(gy * HIN + gx) * CIN + kc * 32 + g * 8);
      const int par = xx & 1, hx = xx >> 1;
      const int f = (hx >> FS) & (NG - 1);
      *(vbf8*)(&h1p[((par * 33 + yy) * 17 + hx) * RS + (g ^ f) * 8]) = v;
    }
    {
      const u16* wfb = g_wfrag + wfo + lane * 8;
      #pragma unroll
      for (int t = 0; t < 9; t++)
        #pragma unroll
        for (int nt = 0; nt < NT; nt++)
          bw[t * NT + nt] =
              *(const vbf8*)(wfb + (size_t)((kc * 9 + t) * NTF + og * NT + nt) * 512);
    }
    __syncthreads();

    #pragma unroll
    for (int t = 0; t < 9; t++) {
      const int ty = t / 3, tx = t % 3;
      const int par = tx & 1;
      const int hx = (lane & 15) + (tx >> 1);
      const int f = (hx >> FS) & (NG - 1);
      #pragma unroll
      for (int mt = 0; mt < 2; mt++) {
        const int y = 2 * (wv * 2 + mt) + ty;
        const u16* ap;
        if constexpr (NG == 4) {
          ap = &h1p[((par * 33 + y) * 17 + hx) * RS + ((kg ^ f) & 3) * 8];
        } else {
          ap = (kg < NG) ? &h1p[((par * 33 + y) * 17 + hx) * RS + ((kg ^ f) & (NG - 1)) * 8]
                         : zbuf;
        }
        vbf8 a = *(const vbf8*)ap;
        #pragma unroll
        for (int nt = 0; nt < NT; nt++)
          acc2[mt][nt] = __builtin_amdgcn_mfma_f32_16x16x32_bf16(
              a, bw[t * NT + nt], acc2[mt][nt], 0, 0, 0);
      }
    }
  }

  if constexpr (REDUCE) {
    #pragma unroll
    for (int nt = 0; nt < NT; nt++) {
      float part = 0.f;
      #pragma unroll
      for (int mt = 0; mt < 2; mt++)
        #pragma unroll
        for (int j = 0; j < 4; j++)
          part += fmaxf(acc2[mt][nt][j], 0.f);
      atomicAdd(&rsum[nt * 16 + ocl], part);
    }
    __syncthreads();
    if (tid < NT * 16)
      atomicAdd(&g_state[gofs + zb2 * COUT + og * NT * 16 + tid],
                rsum[tid] * (1.f / 16384.f));
  } else {
    #pragma unroll
    for (int mt = 0; mt < 2; mt++) {
      const int oy = oy0 + wv * 2 + mt;
      #pragma unroll
      for (int nt = 0; nt < NT; nt++) {
        const int oc = og * NT * 16 + nt * 16 + ocl;
        #pragma unroll
        for (int j = 0; j < 4; j++) {
          const int ox = ox0 + kg * 4 + j;
          out[((size_t)zb2 * HO * HO + (size_t)(oy * HO + ox)) * COUT + oc] =
              f2b(fmaxf(acc2[mt][nt][j], 0.f));
        }
      }
    }
  }
}

// ---------- merged conv3 (WN z<zwn, BL else) ----------
__global__ __launch_bounds__(512, 2) void kc3(
    const u16* __restrict__ inW, const float* __restrict__ bW, u16* __restrict__ outW,
    const u16* __restrict__ inB, const float* __restrict__ bB, u16* __restrict__ outB,
    int zwn)
{
  __shared__ __align__(16) u16 h1sh[35904];
  __shared__ __align__(16) u16 zbuf[8];
  __shared__ float rsum[32];
  const int z = blockIdx.z;
  if (z < zwn)
    k34body<32, 64, 2, 4, 1, false>(inW, bW, WF_WN3, outW, 512, 0, z >> 1, z & 1,
                                    h1sh, zbuf, rsum);
  else
    k34body<16, 32, 2, 2, 1, false>(inB, bB, WF_BL3, outB, 512, 0, z - zwn, 0,
                                    h1sh, zbuf, rsum);
}

// ---------- merged conv4 (WN z<zwn, BL else), fused mean-reduce ----------
__global__ __launch_bounds__(512, 2) void kc4(
    const u16* __restrict__ inW, const float* __restrict__ bW, int gofsW,
    const u16* __restrict__ inB, const float* __restrict__ bB, int gofsB,
    int zwn)
{
  __shared__ __align__(16) u16 h1sh[35904];
  __shared__ __align__(16) u16 zbuf[8];
  __shared__ float rsum[32];
  const int z = blockIdx.z;
  if (z < zwn)
    k34body<64, 64, 2, 4, 2, true>(inW, bW, WF_WN4, nullptr, 256, gofsW, z >> 1, z & 1,
                                   h1sh, zbuf, rsum);
  else
    k34body<32, 32, 2, 4, 1, true>(inB, bB, WF_BL4, nullptr, 256, gofsB, z - zwn, 0,
                                   h1sh, zbuf, rsum);
}

// ---------- FC heads (merged) ----------
template<int CF, int NOUT, bool SIG>
__device__ __forceinline__ void khead_body(
    const float* __restrict__ fw1, const float* __restrict__ fb1,
    const float* __restrict__ fw2, const float* __restrict__ fb2,
    int feato, int outo, float* out_f, float* fc1)
{
  const int tid = threadIdx.x;
  if (tid < 4 * CF) {
    int b = tid / CF, o = tid - b * CF;
    float s = fb1[o];
    for (int i = 0; i < CF; i++)
      s = fmaf(g_state[feato + b * CF + i], fw1[o * CF + i], s);
    fc1[tid] = fmaxf(s, 0.f);
  }
  __syncthreads();
  if (tid < 4 * NOUT) {
    int b = tid / NOUT, n = tid - b * NOUT;
    float s = fb2[n];
    for (int i = 0; i < CF; i++)
      s = fmaf(fc1[b * CF + i], fw2[n * CF + i], s);
    if (SIG) s = 1.f / (1.f + expf(-s));
    g_state[outo + b * NOUT + n] = s;
    if (out_f) out_f[b * NOUT + n] = s;
  }
}

__global__ __launch_bounds__(256) void kheads(
    const float* __restrict__ wfw1, const float* __restrict__ wfb1,
    const float* __restrict__ wfw2, const float* __restrict__ wfb2,
    const float* __restrict__ bfw1, const float* __restrict__ bfb1,
    const float* __restrict__ bfw2, const float* __restrict__ bfb2,
    float* out_w3d)
{
  __shared__ float fc1[256];
  if (blockIdx.x == 0)
    khead_body<64, 8, false>(wfw1, wfb1, wfw2, wfb2, GS_FEATWN, GS_W3D, out_w3d, fc1);
  else
    khead_body<32, 1, true>(bfw1, bfb1, bfw2, bfb2, GS_FEATBL, GS_BLEND, nullptr, fc1);
}

// ---------- fused LUT = clip(w3d @ luts + identity, 0,1) ----------
__global__ __launch_bounds__(256) void kfuse(
    const float* __restrict__ luts, float* __restrict__ outF)
{
  if (blockIdx.x == 0 && threadIdx.x == 0) {
    g_state[GS_ACCS] = 0.f; g_state[GS_ACCS + 1] = 0.f;
  }
  int idx = blockIdx.x * 256 + threadIdx.x;
  if (idx >= 431244) return;
  int n = idx / 107811, m = idx - n * 107811;
  int c = m / 35937, q = m - c * 35937;
  int bq = q / 1089, r2 = q - bq * 1089;
  int gq = r2 / 33, rq = r2 - gq * 33;
  int id = (c == 0) ? rq : (c == 1) ? gq : bq;
  float s = (float)id * (1.f / 32.f);
  #pragma unroll
  for (int k = 0; k < 8; k++)
    s = fmaf(g_state[GS_W3D + n * 8 + k], luts[k * 107811 + m], s);
  s = fminf(fmaxf(s, 0.f), 1.f);
  outF[idx] = s;
}

// ---------- expand fused LUT into 8-corner 64B cell blocks (fp16 AoS) ----------
// Fa2[b][cell(ib,ig,ir)][corner cr=db*4+dg*2+dr] = {R,G,B,0} fp16 -> 64B/cell.
__global__ __launch_bounds__(256) void kexpand(const float* __restrict__ F,
                                               u16* __restrict__ Fa2)
{
  int t = blockIdx.x * 256 + threadIdx.x;   // grid 4096*256 = 1,048,576 exact
  int cr = t & 7;
  int cell = (t >> 3) & 32767;
  int b = t >> 18;
  int ib = cell >> 10, ig = (cell >> 5) & 31, ir = cell & 31;
  int db = cr >> 2, dg = (cr >> 1) & 1, dr = cr & 1;
  const float* Fb = F + (size_t)b * 107811u
                  + (ib + db) * 1089 + (ig + dg) * 33 + (ir + dr);
  vs4 v;
  v[0] = (short)f2h(Fb[0]);
  v[1] = (short)f2h(Fb[35937]);
  v[2] = (short)f2h(Fb[71874]);
  v[3] = 0;
  *(vs4*)(Fa2 + (size_t)t * 4) = v;
}

// ---------- TV + monotonicity reductions over fused ----------
__global__ __launch_bounds__(256) void ktv(const float* __restrict__ f) {
  const int Nr = 418176;
  float tv = 0.f, mn = 0.f;
  for (int e = blockIdx.x * 256 + threadIdx.x; e < 3 * Nr; e += gridDim.x * 256) {
    int dir = e / Nr, j = e - dir * Nr;
    int i, stride; float w;
    if (dir == 0) {
      int r = j & 31; int t = j >> 5;
      int g = t % 33; t /= 33;
      i = t * 1089 + g * 33 + r; stride = 1;
      w = (r == 0 || r == 31) ? 2.f : 1.f;
    } else if (dir == 1) {
      int r = j % 33; int t = j / 33; int g = t & 31; t >>= 5;
      i = t * 1089 + g * 33 + r; stride = 33;
      w = (g == 0 || g == 31) ? 2.f : 1.f;
    } else {
      int r = j % 33; int t = j / 33; int g = t % 33; t /= 33;
      int bb = t & 31; t >>= 5;
      i = (t * 33 + bb) * 1089 + g * 33 + r; stride = 1089;
      w = (bb == 0 || bb == 31) ? 2.f : 1.f;
    }
    float d = f[i] - f[i + stride];
    tv = fmaf(d * d, w, tv);
    mn += fmaxf(d, 0.f);
  }
  __shared__ float r1[256], r2[256];
  r1[threadIdx.x] = tv; r2[threadIdx.x] = mn; __syncthreads();
  for (int st = 128; st > 0; st >>= 1) {
    if (threadIdx.x < st) { r1[threadIdx.x] += r1[threadIdx.x + st];
                            r2[threadIdx.x] += r2[threadIdx.x + st]; }
    __syncthreads();
  }
  if (threadIdx.x == 0) {
    atomicAdd(&g_state[GS_ACCS], r1[0]);
    atomicAdd(&g_state[GS_ACCS + 1], r2[0]);
  }
}

// ---------- trilinear apply, 2x2 px/thread, 8-corner 64B-line gathers ----------
__global__ __launch_bounds__(256) void kapply4(
    const float* __restrict__ x, const u16* __restrict__ Fa2,
    float* __restrict__ out)
{
  if (blockIdx.x == 0 && blockIdx.y == 0 && blockIdx.z == 0 && threadIdx.x == 0) {
    out[OUT_TV] = g_state[GS_ACCS] * (1.f / 418176.f);
    out[OUT_MN] = g_state[GS_ACCS + 1] * (1.f / 418176.f);
  }
  const int b = blockIdx.z;
  const int tx = threadIdx.x & 15, ty = threadIdx.x >> 4;
  const int px0 = blockIdx.x * 32 + tx * 2;
  const int py0 = blockIdx.y * 32 + ty * 2;
  const float a = g_state[GS_BLEND + b];
  const u32* Fu = (const u32*)Fa2;
  const size_t xb0 = (size_t)b * 3145728u;

  vf2 xr[2], xg[2], xbl[2];
  #pragma unroll
  for (int r = 0; r < 2; r++) {
    size_t base = xb0 + (size_t)((py0 + r) << 10) + px0;
    xr[r]  = *(const vf2*)(x + base);
    xg[r]  = *(const vf2*)(x + base + 1048576);
    xbl[r] = *(const vf2*)(x + base + 2097152);
  }

  int cb4[4];
  float fr4[4], fg4[4], fb4[4], xv4[4][3];
  #pragma unroll
  for (int r = 0; r < 2; r++)
    #pragma unroll
    for (int cq = 0; cq < 2; cq++) {
      const int i = r * 2 + cq;
      float vr = xr[r][cq], vg = xg[r][cq], vb = xbl[r][cq];
      xv4[i][0] = vr; xv4[i][1] = vg; xv4[i][2] = vb;
      float sr = fminf(fmaxf(vr, 0.f), 1.f) * 32.f;
      float sg = fminf(fmaxf(vg, 0.f), 1.f) * 32.f;
      float sb = fminf(fmaxf(vb, 0.f), 1.f) * 32.f;
      int ir = min((int)sr, 31), ig = min((int)sg, 31), ib = min((int)sb, 31);
      fr4[i] = sr - ir; fg4[i] = sg - ig; fb4[i] = sb - ib;
      cb4[i] = (b << 15) + ib * 1024 + ig * 32 + ir;   // cell index
    }

  // 16 dwordx4 gathers; the 4 per pixel hit the SAME aligned 64B line
  u32 q[4][4][4];
  #pragma unroll
  for (int i = 0; i < 4; i++) {
    const u32* c0 = Fu + ((size_t)cb4[i] << 4);
    #pragma unroll
    for (int pr = 0; pr < 4; pr++) {
      q[i][pr][0] = c0[pr * 4 + 0]; q[i][pr][1] = c0[pr * 4 + 1];
      q[i][pr][2] = c0[pr * 4 + 2]; q[i][pr][3] = c0[pr * 4 + 3];
    }
  }

  vf2 o0[2], o1[2], o2[2];
  #pragma unroll
  for (int r = 0; r < 2; r++)
    #pragma unroll
    for (int cq = 0; cq < 2; cq++) {
      const int i = r * 2 + cq;
      const float fr = fr4[i], fg = fg4[i], fb = fb4[i];
      #pragma unroll
      for (int c = 0; c < 3; c++) {
        const int k = c >> 1, sh = (c & 1) * 16;
        // corner cr = db*4+dg*2+dr ; q[i][w] holds cr=2w (lo 8B) and 2w+1 (hi 8B)
        float v000 = h2f((u16)(q[i][0][k]     >> sh));
        float v001 = h2f((u16)(q[i][0][2 + k] >> sh));
        float v010 = h2f((u16)(q[i][1][k]     >> sh));
        float v011 = h2f((u16)(q[i][1][2 + k] >> sh));
        float v100 = h2f((u16)(q[i][2][k]     >> sh));
        float v101 = h2f((u16)(q[i][2][2 + k] >> sh));
        float v110 = h2f((u16)(q[i][3][k]     >> sh));
        float v111 = h2f((u16)(q[i][3][2 + k] >> sh));
        float c00 = v000 + fr * (v001 - v000);
        float c01 = v010 + fr * (v011 - v010);
        float c10 = v100 + fr * (v101 - v100);
        float c11 = v110 + fr * (v111 - v110);
        float c0 = c00 + fg * (c01 - c00);
        float c1 = c10 + fg * (c11 - c10);
        float v  = c0 + fb * (c1 - c0);
        float o = fminf(fmaxf((1.f - a) * xv4[i][c] + a * v, 0.f), 1.f);
        if (c == 0) o0[r][cq] = o; else if (c == 1) o1[r][cq] = o; else o2[r][cq] = o;
      }
    }
  #pragma unroll
  for (int r = 0; r < 2; r++) {
    size_t base = (size_t)((py0 + r) << 10) + px0;
    *(vf2*)(out + (size_t)(b * 3 + 0) * 1048576u + base) = o0[r];
    *(vf2*)(out + (size_t)(b * 3 + 1) * 1048576u + base) = o1[r];
    *(vf2*)(out + (size_t)(b * 3 + 2) * 1048576u + base) = o2[r];
  }
}

// ---------- trilinear apply, fallback 1 px/thread, fp32 SoA ----------
__global__ __launch_bounds__(256) void kapply1(
    const float* __restrict__ x, const float* __restrict__ F,
    float* __restrict__ out)
{
  int p = blockIdx.x * 256 + threadIdx.x;
  if (p == 0) {
    out[OUT_TV] = g_state[GS_ACCS] * (1.f / 418176.f);
    out[OUT_MN] = g_state[GS_ACCS + 1] * (1.f / 418176.f);
  }
  int b = p >> 20, yx = p & 1048575;
  size_t base = (size_t)b * 3145728u + yx;
  float xr = x[base];
  float xg = x[base + 1048576];
  float xb = x[base + 2097152];
  float a = g_state[GS_BLEND + b];
  float sr = fminf(fmaxf(xr, 0.f), 1.f) * 32.f;
  float sg = fminf(fmaxf(xg, 0.f), 1.f) * 32.f;
  float sb = fminf(fmaxf(xb, 0.f), 1.f) * 32.f;
  int ir = min((int)sr, 31), ig = min((int)sg, 31), ib = min((int)sb, 31);
  float fr = sr - ir, fg = sg - ig, fb = sb - ib;
  const float* Fb = F + (size_t)b * 107811u + ib * 1089 + ig * 33 + ir;
  #pragma unroll
  for (int c = 0; c < 3; c++) {
    const float* Fc = Fb + c * 35937;
    float v000 = Fc[0],    v001 = Fc[1];
    float v010 = Fc[33],   v011 = Fc[34];
    float v100 = Fc[1089], v101 = Fc[1090];
    float v110 = Fc[1122], v111 = Fc[1123];
    float c00 = v000 + fr * (v001 - v000);
    float c01 = v010 + fr * (v011 - v010);
    float c10 = v100 + fr * (v101 - v100);
    float c11 = v110 + fr * (v111 - v110);
    float c0 = c00 + fg * (c01 - c00);
    float c1 = c10 + fg * (c11 - c10);
    float v  = c0 + fb * (c1 - c0);
    float xv = (c == 0) ? xr : (c == 1) ? xg : xb;
    float o = fminf(fmaxf((1.f - a) * xv + a * v, 0.f), 1.f);
    out[(size_t)(b * 3 + c) * 1048576u + yx] = o;
  }
}

extern "C" void kernel_launch(void* const* d_in, const int* in_sizes, int n_in,
                              void* d_out, int out_size, void* d_ws, size_t ws_size,
                              hipStream_t stream)
{
  (void)in_sizes; (void)n_in; (void)out_size;
  const float* x    = (const float*)d_in[0];
  const float* luts = (const float*)d_in[1];
  const float* wn_b1 = (const float*)d_in[3];
  const float* wn_b2 = (const float*)d_in[5];
  const float* wn_b3 = (const float*)d_in[7];
  const float* wn_b4 = (const float*)d_in[9];
  const float* wn_fw1 = (const float*)d_in[10], *wn_fb1 = (const float*)d_in[11];
  const float* wn_fw2 = (const float*)d_in[12], *wn_fb2 = (const float*)d_in[13];
  const float* bl_b1 = (const float*)d_in[15];
  const float* bl_b2 = (const float*)d_in[17];
  const float* bl_b3 = (const float*)d_in[19];
  const float* bl_b4 = (const float*)d_in[21];
  const float* bl_fw1 = (const float*)d_in[22], *bl_fb1 = (const float*)d_in[23];
  const float* bl_fw2 = (const float*)d_in[24], *bl_fb2 = (const float*)d_in[25];
  float* out = (float*)d_out;
  const bool hasWs = (ws_size >= 50331648u);

  P2Args p2;
  const float* wsrc[8] = {(const float*)d_in[4],  (const float*)d_in[16],
                          (const float*)d_in[6],  (const float*)d_in[8],
                          (const float*)d_in[18], (const float*)d_in[20],
                          (const float*)d_in[2],  (const float*)d_in[14]};
  const int pI[8]   = {32, 16, 32, 64, 16, 32, 3, 3};
  const int pNTF[8] = {2, 1, 4, 4, 2, 2, 2, 1};
  const int pB[8]   = {WF_WN2, WF_BL2, WF_WN3, WF_WN4, WF_BL3, WF_BL4,
                       WF_WN1, WF_BL1};
  for (int l = 0; l < 8; l++) { p2.w[l] = wsrc[l]; p2.I[l] = pI[l];
                                p2.ntf[l] = pNTF[l]; p2.base[l] = pB[l]; }
  kprep2<<<dim3(354), 256, 0, stream>>>(p2);

  if (hasWs) {
    u16* scrA = (u16*)d_ws;                    // WN h2, 2 batches (33.6 MB)
    u16* scrB = (u16*)d_ws + 16777216;         // WN conv3 out (16.8 MB)
    u16* blh2 = (u16*)out;                     // BL h2, 2 batches (16.8 MB)
    u16* blc3 = (u16*)out + 8388608;           // BL conv3 out (8.4 MB)
    u16* Fa2  = (u16*)d_ws;                    // 8-corner LUT blocks (16.8 MB)

    for (int b0 = 0; b0 < 4; b0 += 2) {
      const float* xb = x + (size_t)b0 * 3145728u;
      k12d<<<dim3(32,32,2), 512, 0, stream>>>(xb, wn_b1, wn_b2, bl_b1, bl_b2,
                                              scrA, blh2);
      kc3<<<dim3(16,16,6), 512, 0, stream>>>(scrA, wn_b3, scrB,
                                             blh2, bl_b3, blc3, 4);
      kc4<<<dim3(8,8,6),   512, 0, stream>>>(scrB, wn_b4, GS_FEATWN + b0 * 64,
                                             blc3, bl_b4, GS_FEATBL + b0 * 32, 4);
    }
    kheads<<<2, 256, 0, stream>>>(wn_fw1, wn_fb1, wn_fw2, wn_fb2,
                                  bl_fw1, bl_fb1, bl_fw2, bl_fb2, out + OUT_W3D);

    kfuse<<<1685, 256, 0, stream>>>(luts, out + OUT_FUSED);
    kexpand<<<4096, 256, 0, stream>>>(out + OUT_FUSED, Fa2);
    ktv<<<512, 256, 0, stream>>>(out + OUT_FUSED);
    kapply4<<<dim3(32,32,4), 256, 0, stream>>>(x, Fa2, out);
  } else {
    // 1-batch passes; all scratch inside d_out (37.7 MB < OUT_FUSED @ 50.3 MB)
    u16* h2wF  = (u16*)out;                 // 16.8 MB
    u16* h2bF  = (u16*)out + 8388608;       //  8.4 MB
    u16* wnc3F = (u16*)out + 12582912;      //  8.4 MB
    u16* blc3F = (u16*)out + 16777216;      //  4.2 MB

    for (int b = 0; b < 4; b++) {
      const float* xb = x + (size_t)b * 3145728u;
      k12d<<<dim3(32,32,1), 512, 0, stream>>>(xb, wn_b1, wn_b2, bl_b1, bl_b2,
                                              h2wF, h2bF);
      kc3<<<dim3(16,16,3), 512, 0, stream>>>(h2wF, wn_b3, wnc3F,
                                             h2bF, bl_b3, blc3F, 2);
      kc4<<<dim3(8,8,3),   512, 0, stream>>>(wnc3F, wn_b4, GS_FEATWN + b * 64,
                                             blc3F, bl_b4, GS_FEATBL + b * 32, 2);
    }
    kheads<<<2, 256, 0, stream>>>(wn_fw1, wn_fb1, wn_fw2, wn_fb2,
                                  bl_fw1, bl_fb1, bl_fw2, bl_fb2, out + OUT_W3D);

    kfuse<<<1685, 256, 0, stream>>>(luts, out + OUT_FUSED);
    ktv<<<512, 256, 0, stream>>>(out + OUT_FUSED);
    kapply1<<<16384, 256, 0, stream>>>(x, out + OUT_FUSED, out);
  }
}

// Round 12
// 412.546 us; speedup vs baseline: 1.0503x; 1.0156x over previous
//
#include <hip/hip_runtime.h>
#include <hip/hip_bf16.h>

typedef unsigned short u16;
typedef unsigned int u32;
typedef __attribute__((ext_vector_type(8))) short vbf8;   // 8 bf16 = 4 VGPR
typedef __attribute__((ext_vector_type(4))) short vs4;    // 4 bf16 = 8 B
typedef __attribute__((ext_vector_type(4))) float vf4;    // MFMA acc / float4
typedef __attribute__((ext_vector_type(2))) float vf2;    // float2

// ---------- bf16 <-> f32 ----------
__device__ __forceinline__ float b2f(u16 u) {
  union { unsigned int i; float f; } v; v.i = ((unsigned int)u) << 16; return v.f;
}
// native conversion (RNE) -> compiler emits v_cvt_pk_bf16_f32 for pairs
__device__ __forceinline__ u16 f2b(float f) {
  __hip_bfloat16 h = __float2bfloat16(f);
  return *reinterpret_cast<u16*>(&h);
}
__device__ __forceinline__ u16 f2h(float f) {
  union { _Float16 h; u16 s; } cv; cv.h = (_Float16)f; return cv.s;
}
__device__ __forceinline__ float h2f(u16 u) {
  union { _Float16 h; u16 s; } cv; cv.s = u; return (float)cv.h;
}
// two 8B LDS reads -> one bf16x8 fragment (8B-aligned safe)
__device__ __forceinline__ vbf8 ldpair(const u16* p) {
  vs4 lo = *(const vs4*)p;
  vs4 hi = *(const vs4*)(p + 4);
  return __builtin_shufflevector(lo, hi, 0, 1, 2, 3, 4, 5, 6, 7);
}

// ---------- tiny cross-kernel state ------
__device__ float g_state[512];
#define GS_FEATWN 0      // 256
#define GS_FEATBL 256    // 128
#define GS_W3D    384    // 32
#define GS_BLEND  416    // 4
#define GS_ACCS   420    // 2

// ---------- MFMA-fragment-ordered bf16 conv weights ----------
// conv2..4 (full-K): elem (l,j) = W[oc=nt*16+(l&15)][ic=kc*32+(l>>4)*8+j][t];
//   frag idx = (kc*9+t)*NTF + nt ; ic >= I zero-pad.
// conv1 tap-pair: k = kg*8 + tp*4 + ic; pair starts {0,3,6,2} (g0), {5,8,-,-} (g1);
//   tp=1 taps {1,4,7} (g0 only); ic>=3 or dead -> 0. WN: 2 oc-chunks x 2 groups.
__device__ __align__(16) u16 g_wfrag[90624];
#define WF_WN2 0       // 18 frags (full-K)
#define WF_BL2 9216    //  9
#define WF_WN3 13824   // 36
#define WF_WN4 32256   // 72
#define WF_BL3 69120   // 18 (I=16 zero-pad)
#define WF_BL4 78336   // 18
#define WF_WN1 87552   //  4 (2 oc-chunks x 2 groups)
#define WF_BL1 89600   //  2

// ---------- output layout (fp32 elements) ----------
#define OUT_FUSED 12582912
#define OUT_TV    13014156
#define OUT_MN    13014157
#define OUT_W3D   13014158

// ---------- prep: pack all conv weights into MFMA fragment order ----------
struct P2Args { const float* w[8]; int I[8]; int ntf[8]; int base[8]; };

__global__ __launch_bounds__(256) void kprep2(P2Args a) {
  if (blockIdx.x == 0 && threadIdx.x < 256) {
    g_state[threadIdx.x] = 0.f;
    if (threadIdx.x < 128) g_state[256 + threadIdx.x] = 0.f;
  }
  int i = blockIdx.x * 256 + threadIdx.x;   // grid 354*256 = 90624 exact
  int l = 0;
  #pragma unroll
  for (int k = 1; k < 8; k++) if (i >= a.base[k]) l = k;
  int e2 = i - a.base[l];
  int frag = e2 >> 9, e = e2 & 511;
  int ll = e >> 3, j = e & 7;
  if (l < 6) {
    int NTF = a.ntf[l];
    int kc = frag / (9 * NTF);
    int r = frag - kc * 9 * NTF;
    int t = r / NTF, nt = r - t * NTF;
    int I = a.I[l];
    int oc = nt * 16 + (ll & 15);
    int ic = kc * 32 + (ll >> 4) * 8 + j;
    g_wfrag[i] = (ic < I) ? f2b(a.w[l][(oc * I + ic) * 9 + t]) : (u16)0;
  } else {
    // conv1 tap-pair packing
    int isWN = (l == 6);
    int c2 = isWN ? (frag >> 1) : 0;
    int g = isWN ? (frag & 1) : frag;
    int idx = g * 4 + (ll >> 4);
    int tp = j >> 2, ic = j & 3;
    int tap = (tp == 0)
        ? ((idx == 0) ? 0 : (idx == 1) ? 3 : (idx == 2) ? 6 :
           (idx == 3) ? 2 : (idx == 4) ? 5 : (idx == 5) ? 8 : -1)
        : ((idx == 0) ? 1 : (idx == 1) ? 4 : (idx == 2) ? 7 : -1);
    int oc = c2 * 16 + (ll & 15);
    g_wfrag[i] = (ic < 3 && tap >= 0) ? f2b(a.w[l][oc * 27 + ic * 9 + tap]) : (u16)0;
  }
}

// ---------- merged WN+BL conv1+conv2, 512 thr, 81.6 KB LDS, 2 blk/CU ----------
// xs4 [35][35][4]; h1 32-ch NG=4 for WN (full-K conv2), first half reused by BL.
__global__ __launch_bounds__(512, 4) void k12d(
    const float* __restrict__ x,
    const float* __restrict__ wb1, const float* __restrict__ wb2,
    const float* __restrict__ bb1, const float* __restrict__ bb2,
    u16* __restrict__ h2w, u16* __restrict__ h2b)
{
  __shared__ __align__(16) u16 xs4[4908];    // 35*35*4 + 8 guard = 9,816 B
  __shared__ __align__(16) u16 h1w[35904];   // [2][33][17][32] = 71,808 B
  const int tid = threadIdx.x;
  const int lane = tid & 63, wv = tid >> 6;
  const int ocl = lane & 15;
  const int kg  = lane >> 4;
  const int oy0 = blockIdx.y * 16, ox0 = blockIdx.x * 16;
  const int hy0 = 2 * oy0 - 1, hx0 = 2 * ox0 - 1;
  const float* xb = x + (size_t)blockIdx.z * 3145728u;
  u16* h2wb = h2w + (size_t)blockIdx.z * 8388608u;
  u16* h2bb = h2b + (size_t)blockIdx.z * 4194304u;

  // ---- stage x as 4-ch NHWC bf16 ----
  for (int i = tid; i < 1225; i += 512) {
    int yy = i / 35, xx = i - yy * 35;
    int gy = hy0 - 1 + yy, gx = hx0 - 1 + xx;
    vs4 v = {0, 0, 0, 0};
    if ((unsigned)gy < 1024u && (unsigned)gx < 1024u) {
      const float* pp = xb + (gy << 10) + gx;
      v[0] = (short)f2b(pp[0]);
      v[1] = (short)f2b(pp[1048576]);
      v[2] = (short)f2b(pp[2097152]);
    }
    *(vs4*)(&xs4[(yy * 35 + xx) * 4]) = v;
  }

  // tap-pair B-frag u16 offsets (35-wide rows)
  const int to0 = (kg < 3) ? kg * 140 : 8;        // pair starts taps {0,3,6,2}
  const int to1 = (kg == 0) ? 148 : 288;          // {5,8,dead,dead}

  // WN conv1 weight frags + biases
  vbf8 waW[4];
  float bias1[2][4];
  {
    const u16* wfb = g_wfrag + WF_WN1 + lane * 8;
    #pragma unroll
    for (int q = 0; q < 4; q++) waW[q] = *(const vbf8*)(wfb + q * 512);
    #pragma unroll
    for (int j = 0; j < 4; j++) {
      bias1[0][j] = wb1[kg * 4 + j];
      bias1[1][j] = wb1[16 + kg * 4 + j];
    }
  }
  __syncthreads();

  // ---- conv1 WN: both oc-chunks, shared B-frags; bias as MFMA C-init ----
  for (int pt = wv; pt < 69; pt += 8) {
    const int p = pt * 16 + ocl;
    const bool ok = (p < 1089);
    const int pc = ok ? p : 1088;
    const int py = pc / 33, px = pc - py * 33;
    const u16* pb = xs4 + (py * 35 + px) * 4;
    vbf8 b0 = ldpair(pb + to0);
    vbf8 b1 = ldpair(pb + to1);
    const int par = px & 1, hx = px >> 1;
    const int f = (hx >> 1) & 3;
    const int hb = ((par * 33 + py) * 17 + hx) * 32;
    #pragma unroll
    for (int c = 0; c < 2; c++) {
      vf4 acc;
      acc[0] = bias1[c][0]; acc[1] = bias1[c][1];
      acc[2] = bias1[c][2]; acc[3] = bias1[c][3];
      acc = __builtin_amdgcn_mfma_f32_16x16x32_bf16(waW[c * 2 + 0], b0, acc, 0, 0, 0);
      acc = __builtin_amdgcn_mfma_f32_16x16x32_bf16(waW[c * 2 + 1], b1, acc, 0, 0, 0);
      if (ok) {
        vs4 pk;
        #pragma unroll
        for (int j = 0; j < 4; j++)
          pk[j] = (short)f2b(fmaxf(acc[j], 0.f));
        const int q = (c << 2) + kg;
        *(vs4*)(&h1w[hb + ((q >> 1) ^ f) * 8 + (q & 1) * 4]) = pk;
      }
    }
  }
  __syncthreads();

  // ---- conv2 WN: full-K (NT=2, NG=4) ----
  {
    vbf8 bw[18];
    const u16* wfb = g_wfrag + WF_WN2 + lane * 8;
    #pragma unroll
    for (int i = 0; i < 18; i++)
      bw[i] = *(const vbf8*)(wfb + i * 512);

    vf4 acc2[2][2];
    #pragma unroll
    for (int nt = 0; nt < 2; nt++) {
      float bv = wb2[nt * 16 + ocl];
      vf4 cc; cc[0] = bv; cc[1] = bv; cc[2] = bv; cc[3] = bv;
      acc2[0][nt] = cc; acc2[1][nt] = cc;
    }
    #pragma unroll
    for (int t = 0; t < 9; t++) {
      const int ty = t / 3, tx = t % 3;
      const int par = tx & 1;
      const int hx = ocl + (tx >> 1);
      const int f = (hx >> 1) & 3;
      #pragma unroll
      for (int mt = 0; mt < 2; mt++) {
        const int y = 2 * (wv * 2 + mt) + ty;
        vbf8 a = *(const vbf8*)(&h1w[((par * 33 + y) * 17 + hx) * 32 + ((kg ^ f) & 3) * 8]);
        #pragma unroll
        for (int nt = 0; nt < 2; nt++)
          acc2[mt][nt] = __builtin_amdgcn_mfma_f32_16x16x32_bf16(
              a, bw[t * 2 + nt], acc2[mt][nt], 0, 0, 0);
      }
    }
    #pragma unroll
    for (int mt = 0; mt < 2; mt++) {
      const int oy = oy0 + wv * 2 + mt;
      #pragma unroll
      for (int nt = 0; nt < 2; nt++)
        #pragma unroll
        for (int j = 0; j < 4; j++) {
          const int ox = ox0 + kg * 4 + j;
          h2wb[((size_t)(oy << 9) + ox) * 32 + nt * 16 + ocl] =
              f2b(fmaxf(acc2[mt][nt][j], 0.f));
        }
    }
  }
  __syncthreads();

  // ---- conv1 BL (writes first half of h1w as [2][33][17][16]) ----
  {
    vbf8 wa0 = *(const vbf8*)(g_wfrag + WF_BL1 + lane * 8);
    vbf8 wa1 = *(const vbf8*)(g_wfrag + WF_BL1 + 512 + lane * 8);
    float bias[4];
    #pragma unroll
    for (int j = 0; j < 4; j++) bias[j] = bb1[kg * 4 + j];
    for (int pt = wv; pt < 69; pt += 8) {
      const int p = pt * 16 + ocl;
      const bool ok = (p < 1089);
      const int pc = ok ? p : 1088;
      const int py = pc / 33, px = pc - py * 33;
      const u16* pb = xs4 + (py * 35 + px) * 4;
      vbf8 b0 = ldpair(pb + to0);
      vbf8 b1 = ldpair(pb + to1);
      vf4 acc;
      acc[0] = bias[0]; acc[1] = bias[1]; acc[2] = bias[2]; acc[3] = bias[3];
      acc = __builtin_amdgcn_mfma_f32_16x16x32_bf16(wa0, b0, acc, 0, 0, 0);
      acc = __builtin_amdgcn_mfma_f32_16x16x32_bf16(wa1, b1, acc, 0, 0, 0);
      if (ok) {
        vs4 pk;
        #pragma unroll
        for (int j = 0; j < 4; j++)
          pk[j] = (short)f2b(fmaxf(acc[j], 0.f));
        const int par = px & 1, hx = px >> 1, f = (hx >> 2) & 1;
        *(vs4*)(&h1w[((par * 33 + py) * 17 + hx) * 16 + ((kg >> 1) ^ f) * 8 + (kg & 1) * 4]) = pk;
      }
    }
  }
  __syncthreads();

  // ---- conv2 BL (NT=1, NG=2) ----
  {
    vbf8 bw[9];
    const u16* wfb = g_wfrag + WF_BL2 + lane * 8;
    #pragma unroll
    for (int i = 0; i < 9; i++)
      bw[i] = *(const vbf8*)(wfb + i * 512);
    vf4 accB[2];
    {
      float bv = bb2[ocl];
      vf4 cc; cc[0] = bv; cc[1] = bv; cc[2] = bv; cc[3] = bv;
      accB[0] = cc; accB[1] = cc;
    }
    #pragma unroll
    for (int t = 0; t < 9; t++) {
      const int ty = t / 3, tx = t % 3;
      const int par = tx & 1;
      const int hx = ocl + (tx >> 1);
      const int f = (hx >> 2) & 1;
      #pragma unroll
      for (int mt = 0; mt < 2; mt++) {
        const int y = 2 * (wv * 2 + mt) + ty;
        const u16* ap = (kg < 2)
            ? &h1w[((par * 33 + y) * 17 + hx) * 16 + ((kg ^ f) & 1) * 8]
            : h1w;   // dead lanes: weights are zero
        vbf8 a = *(const vbf8*)ap;
        accB[mt] = __builtin_amdgcn_mfma_f32_16x16x32_bf16(a, bw[t], accB[mt], 0, 0, 0);
      }
    }
    #pragma unroll
    for (int mt = 0; mt < 2; mt++) {
      const int oy = oy0 + wv * 2 + mt;
      #pragma unroll
      for (int j = 0; j < 4; j++) {
        const int ox = ox0 + kg * 4 + j;
        h2bb[((size_t)(oy << 9) + ox) * 16 + ocl] = f2b(fmaxf(accB[mt][j], 0.f));
      }
    }
  }
}

// ---------- stride-2 conv body (conv3/conv4), NHWC in, 512 threads ----------
template<int CIN, int COUT, int NT, int NG, int KC, bool REDUCE>
__device__ __forceinline__ void k34body(
    const u16* __restrict__ in, const float* __restrict__ bia,
    int wfo, u16* __restrict__ out, int HIN, int gofs, int zb2, int og,
    u16* h1p, u16* zbuf, float* rsum)
{
  constexpr int FS = (NG == 4) ? 1 : 2;
  constexpr int NTF = COUT / 16;
  constexpr int RS = NG * 8;
  const int HO = HIN >> 1;
  const int tid = threadIdx.x;
  const int lane = tid & 63, wv = tid >> 6;
  const int oy0 = blockIdx.y * 16, ox0 = blockIdx.x * 16;
  const int iy0 = 2 * oy0 - 1, ix0 = 2 * ox0 - 1;
  const u16* inb = in + (size_t)zb2 * (size_t)HIN * HIN * CIN;

  if (tid < 8) zbuf[tid] = 0;
  if (REDUCE && tid < NT * 16) rsum[tid] = 0.f;

  const int ocl = lane & 15;
  const int kg  = lane >> 4;

  vf4 acc2[2][NT];
  #pragma unroll
  for (int nt = 0; nt < NT; nt++) {
    float bv = bia[og * NT * 16 + nt * 16 + ocl];
    #pragma unroll
    for (int mt = 0; mt < 2; mt++) {
      vf4 c; c[0] = bv; c[1] = bv; c[2] = bv; c[3] = bv;
      acc2[mt][nt] = c;
    }
  }

  vbf8 bw[9 * NT];

  for (int kc = 0; kc < KC; kc++) {
    if (kc) __syncthreads();
    for (int i = tid; i < 33 * 33 * NG; i += 512) {
      int g = i & (NG - 1);
      int pp = i / NG;
      int yy = pp / 33, xx = pp - yy * 33;
      int gy = iy0 + yy, gx = ix0 + xx;
      vbf8 v = {0, 0, 0, 0, 0, 0, 0, 0};
      if ((unsigned)gy < (unsigned)HIN && (unsigned)gx < (unsigned)HIN)
        v = *(const vbf8*)(inb + (size_t)(gy * HIN + gx) * CIN + kc * 32 + g * 8);
      const int par = xx & 1, hx = xx >> 1;
      const int f = (hx >> FS) & (NG - 1);
      *(vbf8*)(&h1p[((par * 33 + yy) * 17 + hx) * RS + (g ^ f) * 8]) = v;
    }
    {
      const u16* wfb = g_wfrag + wfo + lane * 8;
      #pragma unroll
      for (int t = 0; t < 9; t++)
        #pragma unroll
        for (int nt = 0; nt < NT; nt++)
          bw[t * NT + nt] =
              *(const vbf8*)(wfb + (size_t)((kc * 9 + t) * NTF + og * NT + nt) * 512);
    }
    __syncthreads();

    #pragma unroll
    for (int t = 0; t < 9; t++) {
      const int ty = t / 3, tx = t % 3;
      const int par = tx & 1;
      const int hx = (lane & 15) + (tx >> 1);
      const int f = (hx >> FS) & (NG - 1);
      #pragma unroll
      for (int mt = 0; mt < 2; mt++) {
        const int y = 2 * (wv * 2 + mt) + ty;
        const u16* ap;
        if constexpr (NG == 4) {
          ap = &h1p[((par * 33 + y) * 17 + hx) * RS + ((kg ^ f) & 3) * 8];
        } else {
          ap = (kg < NG) ? &h1p[((par * 33 + y) * 17 + hx) * RS + ((kg ^ f) & (NG - 1)) * 8]
                         : zbuf;
        }
        vbf8 a = *(const vbf8*)ap;
        #pragma unroll
        for (int nt = 0; nt < NT; nt++)
          acc2[mt][nt] = __builtin_amdgcn_mfma_f32_16x16x32_bf16(
              a, bw[t * NT + nt], acc2[mt][nt], 0, 0, 0);
      }
    }
  }

  if constexpr (REDUCE) {
    #pragma unroll
    for (int nt = 0; nt < NT; nt++) {
      float part = 0.f;
      #pragma unroll
      for (int mt = 0; mt < 2; mt++)
        #pragma unroll
        for (int j = 0; j < 4; j++)
          part += fmaxf(acc2[mt][nt][j], 0.f);
      atomicAdd(&rsum[nt * 16 + ocl], part);
    }
    __syncthreads();
    if (tid < NT * 16)
      atomicAdd(&g_state[gofs + zb2 * COUT + og * NT * 16 + tid],
                rsum[tid] * (1.f / 16384.f));
  } else {
    #pragma unroll
    for (int mt = 0; mt < 2; mt++) {
      const int oy = oy0 + wv * 2 + mt;
      #pragma unroll
      for (int nt = 0; nt < NT; nt++) {
        const int oc = og * NT * 16 + nt * 16 + ocl;
        #pragma unroll
        for (int j = 0; j < 4; j++) {
          const int ox = ox0 + kg * 4 + j;
          out[((size_t)zb2 * HO * HO + (size_t)(oy * HO + ox)) * COUT + oc] =
              f2b(fmaxf(acc2[mt][nt][j], 0.f));
        }
      }
    }
  }
}

// ---------- merged conv3 (WN z<zwn, BL else) ----------
__global__ __launch_bounds__(512, 2) void kc3(
    const u16* __restrict__ inW, const float* __restrict__ bW, u16* __restrict__ outW,
    const u16* __restrict__ inB, const float* __restrict__ bB, u16* __restrict__ outB,
    int zwn)
{
  __shared__ __align__(16) u16 h1sh[35904];
  __shared__ __align__(16) u16 zbuf[8];
  __shared__ float rsum[32];
  const int z = blockIdx.z;
  if (z < zwn)
    k34body<32, 64, 2, 4, 1, false>(inW, bW, WF_WN3, outW, 512, 0, z >> 1, z & 1,
                                    h1sh, zbuf, rsum);
  else
    k34body<16, 32, 2, 2, 1, false>(inB, bB, WF_BL3, outB, 512, 0, z - zwn, 0,
                                    h1sh, zbuf, rsum);
}

// ---------- merged conv4 (WN z<zwn, BL else), fused mean-reduce ----------
__global__ __launch_bounds__(512, 2) void kc4(
    const u16* __restrict__ inW, const float* __restrict__ bW, int gofsW,
    const u16* __restrict__ inB, const float* __restrict__ bB, int gofsB,
    int zwn)
{
  __shared__ __align__(16) u16 h1sh[35904];
  __shared__ __align__(16) u16 zbuf[8];
  __shared__ float rsum[32];
  const int z = blockIdx.z;
  if (z < zwn)
    k34body<64, 64, 2, 4, 2, true>(inW, bW, WF_WN4, nullptr, 256, gofsW, z >> 1, z & 1,
                                   h1sh, zbuf, rsum);
  else
    k34body<32, 32, 2, 4, 1, true>(inB, bB, WF_BL4, nullptr, 256, gofsB, z - zwn, 0,
                                   h1sh, zbuf, rsum);
}

// ---------- FC heads (merged) ----------
template<int CF, int NOUT, bool SIG>
__device__ __forceinline__ void khead_body(
    const float* __restrict__ fw1, const float* __restrict__ fb1,
    const float* __restrict__ fw2, const float* __restrict__ fb2,
    int feato, int outo, float* out_f, float* fc1)
{
  const int tid = threadIdx.x;
  if (tid < 4 * CF) {
    int b = tid / CF, o = tid - b * CF;
    float s = fb1[o];
    for (int i = 0; i < CF; i++)
      s = fmaf(g_state[feato + b * CF + i], fw1[o * CF + i], s);
    fc1[tid] = fmaxf(s, 0.f);
  }
  __syncthreads();
  if (tid < 4 * NOUT) {
    int b = tid / NOUT, n = tid - b * NOUT;
    float s = fb2[n];
    for (int i = 0; i < CF; i++)
      s = fmaf(fc1[b * CF + i], fw2[n * CF + i], s);
    if (SIG) s = 1.f / (1.f + expf(-s));
    g_state[outo + b * NOUT + n] = s;
    if (out_f) out_f[b * NOUT + n] = s;
  }
}

__global__ __launch_bounds__(256) void kheads(
    const float* __restrict__ wfw1, const float* __restrict__ wfb1,
    const float* __restrict__ wfw2, const float* __restrict__ wfb2,
    const float* __restrict__ bfw1, const float* __restrict__ bfb1,
    const float* __restrict__ bfw2, const float* __restrict__ bfb2,
    float* out_w3d)
{
  __shared__ float fc1[256];
  if (blockIdx.x == 0)
    khead_body<64, 8, false>(wfw1, wfb1, wfw2, wfb2, GS_FEATWN, GS_W3D, out_w3d, fc1);
  else
    khead_body<32, 1, true>(bfw1, bfb1, bfw2, bfb2, GS_FEATBL, GS_BLEND, nullptr, fc1);
}

// ---------- fused LUT = clip(w3d @ luts + identity, 0,1) ----------
__global__ __launch_bounds__(256) void kfuse(
    const float* __restrict__ luts, float* __restrict__ outF)
{
  if (blockIdx.x == 0 && threadIdx.x == 0) {
    g_state[GS_ACCS] = 0.f; g_state[GS_ACCS + 1] = 0.f;
  }
  int idx = blockIdx.x * 256 + threadIdx.x;
  if (idx >= 431244) return;
  int n = idx / 107811, m = idx - n * 107811;
  int c = m / 35937, q = m - c * 35937;
  int bq = q / 1089, r2 = q - bq * 1089;
  int gq = r2 / 33, rq = r2 - gq * 33;
  int id = (c == 0) ? rq : (c == 1) ? gq : bq;
  float s = (float)id * (1.f / 32.f);
  #pragma unroll
  for (int k = 0; k < 8; k++)
    s = fmaf(g_state[GS_W3D + n * 8 + k], luts[k * 107811 + m], s);
  s = fminf(fmaxf(s, 0.f), 1.f);
  outF[idx] = s;
}

// ---------- expand fused LUT into 8-corner 64B cell blocks (fp16 AoS) ----------
// Thread handles 2 adjacent corners (dr=0,1) -> one 16B write.
__global__ __launch_bounds__(256) void kexpand(const float* __restrict__ F,
                                               u16* __restrict__ Fa2)
{
  int t = blockIdx.x * 256 + threadIdx.x;   // grid 2048*256 = 524288 exact
  int cp = t & 3;                 // corner-pair: db*2+dg
  int cell = (t >> 2) & 32767;
  int b = t >> 17;
  int ib = cell >> 10, ig = (cell >> 5) & 31, ir = cell & 31;
  int db = cp >> 1, dg = cp & 1;
  const float* Fb = F + (size_t)b * 107811u
                  + (ib + db) * 1089 + (ig + dg) * 33 + ir;
  vbf8 v;
  v[0] = (short)f2h(Fb[0]);     v[1] = (short)f2h(Fb[35937]);
  v[2] = (short)f2h(Fb[71874]); v[3] = 0;
  v[4] = (short)f2h(Fb[1]);     v[5] = (short)f2h(Fb[35938]);
  v[6] = (short)f2h(Fb[71875]); v[7] = 0;
  *(vbf8*)(Fa2 + (size_t)t * 8) = v;
}

// ---------- TV + monotonicity reductions over fused ----------
__global__ __launch_bounds__(256) void ktv(const float* __restrict__ f) {
  const int Nr = 418176;
  float tv = 0.f, mn = 0.f;
  for (int e = blockIdx.x * 256 + threadIdx.x; e < 3 * Nr; e += gridDim.x * 256) {
    int dir = e / Nr, j = e - dir * Nr;
    int i, stride; float w;
    if (dir == 0) {
      int r = j & 31; int t = j >> 5;
      int g = t % 33; t /= 33;
      i = t * 1089 + g * 33 + r; stride = 1;
      w = (r == 0 || r == 31) ? 2.f : 1.f;
    } else if (dir == 1) {
      int r = j % 33; int t = j / 33; int g = t & 31; t >>= 5;
      i = t * 1089 + g * 33 + r; stride = 33;
      w = (g == 0 || g == 31) ? 2.f : 1.f;
    } else {
      int r = j % 33; int t = j / 33; int g = t % 33; t /= 33;
      int bb = t & 31; t >>= 5;
      i = (t * 33 + bb) * 1089 + g * 33 + r; stride = 1089;
      w = (bb == 0 || bb == 31) ? 2.f : 1.f;
    }
    float d = f[i] - f[i + stride];
    tv = fmaf(d * d, w, tv);
    mn += fmaxf(d, 0.f);
  }
  __shared__ float r1[256], r2[256];
  r1[threadIdx.x] = tv; r2[threadIdx.x] = mn; __syncthreads();
  for (int st = 128; st > 0; st >>= 1) {
    if (threadIdx.x < st) { r1[threadIdx.x] += r1[threadIdx.x + st];
                            r2[threadIdx.x] += r2[threadIdx.x + st]; }
    __syncthreads();
  }
  if (threadIdx.x == 0) {
    atomicAdd(&g_state[GS_ACCS], r1[0]);
    atomicAdd(&g_state[GS_ACCS + 1], r2[0]);
  }
}

// ---------- trilinear apply, 2x2 px/thread, 8-corner 64B-line gathers ----------
__global__ __launch_bounds__(256) void kapply4(
    const float* __restrict__ x, const u16* __restrict__ Fa2,
    float* __restrict__ out)
{
  if (blockIdx.x == 0 && blockIdx.y == 0 && blockIdx.z == 0 && threadIdx.x == 0) {
    out[OUT_TV] = g_state[GS_ACCS] * (1.f / 418176.f);
    out[OUT_MN] = g_state[GS_ACCS + 1] * (1.f / 418176.f);
  }
  const int b = blockIdx.z;
  const int tx = threadIdx.x & 15, ty = threadIdx.x >> 4;
  const int px0 = blockIdx.x * 32 + tx * 2;
  const int py0 = blockIdx.y * 32 + ty * 2;
  const float a = g_state[GS_BLEND + b];
  const u32* Fu = (const u32*)Fa2;
  const size_t xb0 = (size_t)b * 3145728u;

  vf2 xr[2], xg[2], xbl[2];
  #pragma unroll
  for (int r = 0; r < 2; r++) {
    size_t base = xb0 + (size_t)((py0 + r) << 10) + px0;
    xr[r]  = *(const vf2*)(x + base);
    xg[r]  = *(const vf2*)(x + base + 1048576);
    xbl[r] = *(const vf2*)(x + base + 2097152);
  }

  int cb4[4];
  float fr4[4], fg4[4], fb4[4], xv4[4][3];
  #pragma unroll
  for (int r = 0; r < 2; r++)
    #pragma unroll
    for (int cq = 0; cq < 2; cq++) {
      const int i = r * 2 + cq;
      float vr = xr[r][cq], vg = xg[r][cq], vb = xbl[r][cq];
      xv4[i][0] = vr; xv4[i][1] = vg; xv4[i][2] = vb;
      float sr = fminf(fmaxf(vr, 0.f), 1.f) * 32.f;
      float sg = fminf(fmaxf(vg, 0.f), 1.f) * 32.f;
      float sb = fminf(fmaxf(vb, 0.f), 1.f) * 32.f;
      int ir = min((int)sr, 31), ig = min((int)sg, 31), ib = min((int)sb, 31);
      fr4[i] = sr - ir; fg4[i] = sg - ig; fb4[i] = sb - ib;
      cb4[i] = (b << 15) + ib * 1024 + ig * 32 + ir;   // cell index
    }

  // 16 dwordx4 gathers; the 4 per pixel hit the SAME aligned 64B line
  u32 q[4][4][4];
  #pragma unroll
  for (int i = 0; i < 4; i++) {
    const u32* c0 = Fu + ((size_t)cb4[i] << 4);
    #pragma unroll
    for (int pr = 0; pr < 4; pr++) {
      q[i][pr][0] = c0[pr * 4 + 0]; q[i][pr][1] = c0[pr * 4 + 1];
      q[i][pr][2] = c0[pr * 4 + 2]; q[i][pr][3] = c0[pr * 4 + 3];
    }
  }

  vf2 o0[2], o1[2], o2[2];
  #pragma unroll
  for (int r = 0; r < 2; r++)
    #pragma unroll
    for (int cq = 0; cq < 2; cq++) {
      const int i = r * 2 + cq;
      const float fr = fr4[i], fg = fg4[i], fb = fb4[i];
      #pragma unroll
      for (int c = 0; c < 3; c++) {
        const int k = c >> 1, sh = (c & 1) * 16;
        float v000 = h2f((u16)(q[i][0][k]     >> sh));
        float v001 = h2f((u16)(q[i][0][2 + k] >> sh));
        float v010 = h2f((u16)(q[i][1][k]     >> sh));
        float v011 = h2f((u16)(q[i][1][2 + k] >> sh));
        float v100 = h2f((u16)(q[i][2][k]     >> sh));
        float v101 = h2f((u16)(q[i][2][2 + k] >> sh));
        float v110 = h2f((u16)(q[i][3][k]     >> sh));
        float v111 = h2f((u16)(q[i][3][2 + k] >> sh));
        float c00 = v000 + fr * (v001 - v000);
        float c01 = v010 + fr * (v011 - v010);
        float c10 = v100 + fr * (v101 - v100);
        float c11 = v110 + fr * (v111 - v110);
        float c0 = c00 + fg * (c01 - c00);
        float c1 = c10 + fg * (c11 - c10);
        float v  = c0 + fb * (c1 - c0);
        float o = fminf(fmaxf((1.f - a) * xv4[i][c] + a * v, 0.f), 1.f);
        if (c == 0) o0[r][cq] = o; else if (c == 1) o1[r][cq] = o; else o2[r][cq] = o;
      }
    }
  #pragma unroll
  for (int r = 0; r < 2; r++) {
    size_t base = (size_t)((py0 + r) << 10) + px0;
    *(vf2*)(out + (size_t)(b * 3 + 0) * 1048576u + base) = o0[r];
    *(vf2*)(out + (size_t)(b * 3 + 1) * 1048576u + base) = o1[r];
    *(vf2*)(out + (size_t)(b * 3 + 2) * 1048576u + base) = o2[r];
  }
}

// ---------- trilinear apply, fallback 1 px/thread, fp32 SoA ----------
__global__ __launch_bounds__(256) void kapply1(
    const float* __restrict__ x, const float* __restrict__ F,
    float* __restrict__ out)
{
  int p = blockIdx.x * 256 + threadIdx.x;
  if (p == 0) {
    out[OUT_TV] = g_state[GS_ACCS] * (1.f / 418176.f);
    out[OUT_MN] = g_state[GS_ACCS + 1] * (1.f / 418176.f);
  }
  int b = p >> 20, yx = p & 1048575;
  size_t base = (size_t)b * 3145728u + yx;
  float xr = x[base];
  float xg = x[base + 1048576];
  float xb = x[base + 2097152];
  float a = g_state[GS_BLEND + b];
  float sr = fminf(fmaxf(xr, 0.f), 1.f) * 32.f;
  float sg = fminf(fmaxf(xg, 0.f), 1.f) * 32.f;
  float sb = fminf(fmaxf(xb, 0.f), 1.f) * 32.f;
  int ir = min((int)sr, 31), ig = min((int)sg, 31), ib = min((int)sb, 31);
  float fr = sr - ir, fg = sg - ig, fb = sb - ib;
  const float* Fb = F + (size_t)b * 107811u + ib * 1089 + ig * 33 + ir;
  #pragma unroll
  for (int c = 0; c < 3; c++) {
    const float* Fc = Fb + c * 35937;
    float v000 = Fc[0],    v001 = Fc[1];
    float v010 = Fc[33],   v011 = Fc[34];
    float v100 = Fc[1089], v101 = Fc[1090];
    float v110 = Fc[1122], v111 = Fc[1123];
    float c00 = v000 + fr * (v001 - v000);
    float c01 = v010 + fr * (v011 - v010);
    float c10 = v100 + fr * (v101 - v100);
    float c11 = v110 + fr * (v111 - v110);
    float c0 = c00 + fg * (c01 - c00);
    float c1 = c10 + fg * (c11 - c10);
    float v  = c0 + fb * (c1 - c0);
    float xv = (c == 0) ? xr : (c == 1) ? xg : xb;
    float o = fminf(fmaxf((1.f - a) * xv + a * v, 0.f), 1.f);
    out[(size_t)(b * 3 + c) * 1048576u + yx] = o;
  }
}

extern "C" void kernel_launch(void* const* d_in, const int* in_sizes, int n_in,
                              void* d_out, int out_size, void* d_ws, size_t ws_size,
                              hipStream_t stream)
{
  (void)in_sizes; (void)n_in; (void)out_size;
  const float* x    = (const float*)d_in[0];
  const float* luts = (const float*)d_in[1];
  const float* wn_b1 = (const float*)d_in[3];
  const float* wn_b2 = (const float*)d_in[5];
  const float* wn_b3 = (const float*)d_in[7];
  const float* wn_b4 = (const float*)d_in[9];
  const float* wn_fw1 = (const float*)d_in[10], *wn_fb1 = (const float*)d_in[11];
  const float* wn_fw2 = (const float*)d_in[12], *wn_fb2 = (const float*)d_in[13];
  const float* bl_b1 = (const float*)d_in[15];
  const float* bl_b2 = (const float*)d_in[17];
  const float* bl_b3 = (const float*)d_in[19];
  const float* bl_b4 = (const float*)d_in[21];
  const float* bl_fw1 = (const float*)d_in[22], *bl_fb1 = (const float*)d_in[23];
  const float* bl_fw2 = (const float*)d_in[24], *bl_fb2 = (const float*)d_in[25];
  float* out = (float*)d_out;
  const bool hasWs = (ws_size >= 50331648u);

  P2Args p2;
  const float* wsrc[8] = {(const float*)d_in[4],  (const float*)d_in[16],
                          (const float*)d_in[6],  (const float*)d_in[8],
                          (const float*)d_in[18], (const float*)d_in[20],
                          (const float*)d_in[2],  (const float*)d_in[14]};
  const int pI[8]   = {32, 16, 32, 64, 16, 32, 3, 3};
  const int pNTF[8] = {2, 1, 4, 4, 2, 2, 2, 1};
  const int pB[8]   = {WF_WN2, WF_BL2, WF_WN3, WF_WN4, WF_BL3, WF_BL4,
                       WF_WN1, WF_BL1};
  for (int l = 0; l < 8; l++) { p2.w[l] = wsrc[l]; p2.I[l] = pI[l];
                                p2.ntf[l] = pNTF[l]; p2.base[l] = pB[l]; }
  kprep2<<<dim3(354), 256, 0, stream>>>(p2);

  if (hasWs) {
    u16* scrA = (u16*)d_ws;                    // WN h2, 2 batches (33.6 MB)
    u16* scrB = (u16*)d_ws + 16777216;         // WN conv3 out (16.8 MB)
    u16* blh2 = (u16*)out;                     // BL h2, 2 batches (16.8 MB)
    u16* blc3 = (u16*)out + 8388608;           // BL conv3 out (8.4 MB)
    u16* Fa2  = (u16*)d_ws;                    // 8-corner LUT blocks (16.8 MB)

    for (int b0 = 0; b0 < 4; b0 += 2) {
      const float* xb = x + (size_t)b0 * 3145728u;
      k12d<<<dim3(32,32,2), 512, 0, stream>>>(xb, wn_b1, wn_b2, bl_b1, bl_b2,
                                              scrA, blh2);
      kc3<<<dim3(16,16,6), 512, 0, stream>>>(scrA, wn_b3, scrB,
                                             blh2, bl_b3, blc3, 4);
      kc4<<<dim3(8,8,6),   512, 0, stream>>>(scrB, wn_b4, GS_FEATWN + b0 * 64,
                                             blc3, bl_b4, GS_FEATBL + b0 * 32, 4);
    }
    kheads<<<2, 256, 0, stream>>>(wn_fw1, wn_fb1, wn_fw2, wn_fb2,
                                  bl_fw1, bl_fb1, bl_fw2, bl_fb2, out + OUT_W3D);

    kfuse<<<1685, 256, 0, stream>>>(luts, out + OUT_FUSED);
    kexpand<<<2048, 256, 0, stream>>>(out + OUT_FUSED, Fa2);
    ktv<<<512, 256, 0, stream>>>(out + OUT_FUSED);
    kapply4<<<dim3(32,32,4), 256, 0, stream>>>(x, Fa2, out);
  } else {
    // 1-batch passes; all scratch inside d_out (37.7 MB < OUT_FUSED @ 50.3 MB)
    u16* h2wF  = (u16*)out;                 // 16.8 MB
    u16* h2bF  = (u16*)out + 8388608;       //  8.4 MB
    u16* wnc3F = (u16*)out + 12582912;      //  8.4 MB
    u16* blc3F = (u16*)out + 16777216;      //  4.2 MB

    for (int b = 0; b < 4; b++) {
      const float* xb = x + (size_t)b * 3145728u;
      k12d<<<dim3(32,32,1), 512, 0, stream>>>(xb, wn_b1, wn_b2, bl_b1, bl_b2,
                                              h2wF, h2bF);
      kc3<<<dim3(16,16,3), 512, 0, stream>>>(h2wF, wn_b3, wnc3F,
                                             h2bF, bl_b3, blc3F, 2);
      kc4<<<dim3(8,8,3),   512, 0, stream>>>(wnc3F, wn_b4, GS_FEATWN + b * 64,
                                             blc3F, bl_b4, GS_FEATBL + b * 32, 2);
    }
    kheads<<<2, 256, 0, stream>>>(wn_fw1, wn_fb1, wn_fw2, wn_fb2,
                                  bl_fw1, bl_fb1, bl_fw2, bl_fb2, out + OUT_W3D);

    kfuse<<<1685, 256, 0, stream>>>(luts, out + OUT_FUSED);
    ktv<<<512, 256, 0, stream>>>(out + OUT_FUSED);
    kapply1<<<16384, 256, 0, stream>>>(x, out + OUT_FUSED, out);
  }
}